// Round 1
// baseline (1000.720 us; speedup 1.0000x reference)
//
#include <hip/hip_runtime.h>
#include <math.h>

#define NEGS 0.2f
#define EPSBN 1e-5f

static __device__ __forceinline__ float lrelu(float x){ return x > 0.f ? x : NEGS*x; }

// ---------------- transpose W [R][C] -> Wt [C][R] ----------------
__global__ void k_transpose(const float* __restrict__ in, float* __restrict__ out, int R, int C){
  int i = blockIdx.x*256 + threadIdx.x;
  if (i >= R*C) return;
  int r = i / C, c = i - r*C;
  out[c*R + r] = in[i];
}

// ---------------- CSR build ----------------
__global__ void k_deg(const int* __restrict__ ei, int E, int N, int* __restrict__ deg){
  int i = blockIdx.x*256 + threadIdx.x;
  if (i >= E + N) return;
  int d = (i < E) ? ei[E + i] : (i - E);
  atomicAdd(&deg[d], 1);
}

__global__ void k_scan1(const int* __restrict__ deg, int* __restrict__ incl,
                        int* __restrict__ partials, int n){
  __shared__ int sd[256];
  int tid = threadIdx.x;
  int base = blockIdx.x*1024 + tid*4;
  int v[4]; int s = 0;
  #pragma unroll
  for (int j=0;j<4;++j){ int idx = base+j; v[j] = (idx<n)? deg[idx] : 0; s += v[j]; }
  sd[tid] = s; __syncthreads();
  for (int off=1; off<256; off<<=1){
    int t = (tid>=off)? sd[tid-off] : 0;
    __syncthreads();
    sd[tid] += t;
    __syncthreads();
  }
  int run = sd[tid] - s;
  #pragma unroll
  for (int j=0;j<4;++j){ int idx = base+j; run += v[j]; if (idx<n) incl[idx] = run; }
  if (tid==255) partials[blockIdx.x] = sd[255];
}

__global__ void k_scan2(int* partials, int nb){
  __shared__ int sd[256];
  int tid = threadIdx.x;
  sd[tid] = (tid<nb)? partials[tid] : 0;
  __syncthreads();
  for (int off=1; off<256; off<<=1){
    int t = (tid>=off)? sd[tid-off] : 0;
    __syncthreads();
    sd[tid] += t;
    __syncthreads();
  }
  if (tid<nb) partials[tid] = sd[tid];
}

__global__ void k_scan3(int* __restrict__ offs, const int* __restrict__ partials, int n){
  int i = blockIdx.x*256 + threadIdx.x;
  if (i == 0) offs[0] = 0;
  if (i >= n) return;
  int b = i >> 10;
  if (b > 0) offs[i+1] += partials[b-1];
}

__global__ void k_scatter(const int* __restrict__ ei, int E, int N,
                          const int* __restrict__ offs, int* __restrict__ cursor,
                          int* __restrict__ csr){
  int i = blockIdx.x*256 + threadIdx.x;
  if (i >= E + N) return;
  int s, d;
  if (i < E){ s = ei[i]; d = ei[E+i]; } else { s = i - E; d = i - E; }
  int pos = offs[d] + atomicAdd(&cursor[d], 1);
  csr[pos] = s;
}

// ---------------- GEMM: Y[n][o] = sum_k X[n][k] * Wt[k][o], 128x128 ----------------
__global__ __launch_bounds__(256) void k_gemm128(const float* __restrict__ X,
                                                 const float* __restrict__ Wt,
                                                 float* __restrict__ Y, int n){
  __shared__ float xt[128*36];   // xt[k*36 + r], r in [0,32)
  int tid = threadIdx.x;
  int r0 = blockIdx.x * 32;
  {
    int r = tid >> 3;
    int c0 = (tid & 7) * 16;
    int row = r0 + r;
    const float4* src = (const float4*)(X + (size_t)row*128 + c0);
    #pragma unroll
    for (int j=0;j<4;++j){
      float4 v = (row < n) ? src[j] : make_float4(0.f,0.f,0.f,0.f);
      int k = c0 + j*4;
      xt[(k+0)*36 + r] = v.x;
      xt[(k+1)*36 + r] = v.y;
      xt[(k+2)*36 + r] = v.z;
      xt[(k+3)*36 + r] = v.w;
    }
  }
  __syncthreads();
  int tc = tid & 31, tr = tid >> 5;
  float acc[4][4] = {};
  #pragma unroll 4
  for (int k=0;k<128;++k){
    float4 wv = *(const float4*)(Wt + k*128 + tc*4);
    float4 xv = *(const float4*)(&xt[k*36 + tr*4]);
    float xv4[4] = {xv.x, xv.y, xv.z, xv.w};
    float wv4[4] = {wv.x, wv.y, wv.z, wv.w};
    #pragma unroll
    for (int u=0;u<4;++u)
      #pragma unroll
      for (int v=0;v<4;++v)
        acc[u][v] = fmaf(xv4[u], wv4[v], acc[u][v]);
  }
  #pragma unroll
  for (int u=0;u<4;++u){
    int row = r0 + tr*4 + u;
    if (row < n)
      *(float4*)(Y + (size_t)row*128 + tc*4) =
        make_float4(acc[u][0], acc[u][1], acc[u][2], acc[u][3]);
  }
}

// ---------------- attention logits: ALs[n][h] = sum_c H[n][h*32+c]*as[h][c] ----------------
__global__ void k_al(const float* __restrict__ H, const float* __restrict__ as_,
                     const float* __restrict__ ad_, float* __restrict__ ALs,
                     float* __restrict__ ALd, int n){
  int node = blockIdx.x*8 + (threadIdx.x >> 5);
  int lane = threadIdx.x & 31;
  if (node >= n) return;
  int hd = lane >> 3;
  float4 hv = *(const float4*)(H + (size_t)node*128 + lane*4);
  float4 av = *(const float4*)(as_ + hd*32 + (lane&7)*4);
  float4 dv = *(const float4*)(ad_ + hd*32 + (lane&7)*4);
  float ps = hv.x*av.x + hv.y*av.y + hv.z*av.z + hv.w*av.w;
  float pd = hv.x*dv.x + hv.y*dv.y + hv.z*dv.z + hv.w*dv.w;
  ps += __shfl_xor(ps,1); ps += __shfl_xor(ps,2); ps += __shfl_xor(ps,4);
  pd += __shfl_xor(pd,1); pd += __shfl_xor(pd,2); pd += __shfl_xor(pd,4);
  if ((lane & 7) == 0){ ALs[node*4+hd] = ps; ALd[node*4+hd] = pd; }
}

// ---------------- fused GAT aggregation + bias + BN + ReLU (128 feats, 4 heads) ----------------
__global__ void k_agg128(const float* __restrict__ H, const float* __restrict__ ALs,
                         const float* __restrict__ ALd, const int* __restrict__ offs,
                         const int* __restrict__ csr,
                         const float* __restrict__ bias, const float* __restrict__ gam,
                         const float* __restrict__ bet, const float* __restrict__ mean,
                         const float* __restrict__ var, float* __restrict__ out, int n){
  int node = blockIdx.x*8 + (threadIdx.x >> 5);
  int lane = threadIdx.x & 31;
  if (node >= n) return;
  int hd = lane >> 3;
  int beg = offs[node], end = offs[node+1];
  float4 ald4 = *(const float4*)(ALd + node*4);
  // phase 1: per-head segment max (lanes parallel over edges)
  float m0=-1e30f, m1=-1e30f, m2=-1e30f, m3=-1e30f;
  for (int e = beg + lane; e < end; e += 32){
    int s = csr[e];
    float4 a = *(const float4*)(ALs + s*4);
    m0 = fmaxf(m0, lrelu(a.x + ald4.x));
    m1 = fmaxf(m1, lrelu(a.y + ald4.y));
    m2 = fmaxf(m2, lrelu(a.z + ald4.z));
    m3 = fmaxf(m3, lrelu(a.w + ald4.w));
  }
  #pragma unroll
  for (int off=1; off<32; off<<=1){
    m0 = fmaxf(m0, __shfl_xor(m0, off));
    m1 = fmaxf(m1, __shfl_xor(m1, off));
    m2 = fmaxf(m2, __shfl_xor(m2, off));
    m3 = fmaxf(m3, __shfl_xor(m3, off));
  }
  float mh   = (hd==0) ? m0 : (hd==1) ? m1 : (hd==2) ? m2 : m3;
  float aldh = (hd==0) ? ald4.x : (hd==1) ? ald4.y : (hd==2) ? ald4.z : ald4.w;
  // phase 2: serial over edges, lanes parallel over features
  float4 acc = make_float4(0.f,0.f,0.f,0.f);
  float wsum = 0.f;
  for (int e = beg; e < end; ++e){
    int s = csr[e];
    float als = ALs[s*4 + hd];
    float w = __expf(lrelu(als + aldh) - mh);
    wsum += w;
    float4 hv = *(const float4*)(H + (size_t)s*128 + lane*4);
    acc.x = fmaf(w, hv.x, acc.x);
    acc.y = fmaf(w, hv.y, acc.y);
    acc.z = fmaf(w, hv.z, acc.z);
    acc.w = fmaf(w, hv.w, acc.w);
  }
  float inv = 1.f / wsum;
  int c = lane*4;
  float4 b4 = *(const float4*)(bias+c);
  float4 g4 = *(const float4*)(gam+c);
  float4 e4 = *(const float4*)(bet+c);
  float4 u4 = *(const float4*)(mean+c);
  float4 v4 = *(const float4*)(var+c);
  float o0 = (acc.x*inv + b4.x - u4.x) * rsqrtf(v4.x + EPSBN) * g4.x + e4.x;
  float o1 = (acc.y*inv + b4.y - u4.y) * rsqrtf(v4.y + EPSBN) * g4.y + e4.y;
  float o2 = (acc.z*inv + b4.z - u4.z) * rsqrtf(v4.z + EPSBN) * g4.z + e4.z;
  float o3 = (acc.w*inv + b4.w - u4.w) * rsqrtf(v4.w + EPSBN) * g4.w + e4.w;
  *(float4*)(out + (size_t)node*128 + c) =
      make_float4(fmaxf(o0,0.f), fmaxf(o1,0.f), fmaxf(o2,0.f), fmaxf(o3,0.f));
}

// ---------------- output layer GEMM (128->40) + attention logits ----------------
__global__ void k_gemm40(const float* __restrict__ X, const float* __restrict__ Wt2,
                         const float* __restrict__ as2, const float* __restrict__ ad2,
                         float* __restrict__ H2, float* __restrict__ al2s,
                         float* __restrict__ al2d, int n){
  int lane = threadIdx.x & 63;
  int row = blockIdx.x*4 + (threadIdx.x >> 6);
  if (row >= n) return;
  float xr0 = X[(size_t)row*128 + lane];
  float xr1 = X[(size_t)row*128 + 64 + lane];
  int ci = (lane < 40) ? lane : 0;
  float acc = 0.f;
  #pragma unroll 8
  for (int k=0;k<128;++k){
    float xk = __shfl((k < 64) ? xr0 : xr1, k & 63);
    acc = fmaf(xk, Wt2[k*40 + ci], acc);
  }
  if (lane >= 40) acc = 0.f;
  float ps = acc * as2[ci];
  float pd = acc * ad2[ci];
  if (lane >= 40){ ps = 0.f; pd = 0.f; }
  #pragma unroll
  for (int m=1; m<64; m<<=1){ ps += __shfl_xor(ps, m); pd += __shfl_xor(pd, m); }
  if (lane < 40) H2[(size_t)row*40 + lane] = acc;
  if (lane == 0){ al2s[row] = ps; al2d[row] = pd; }
}

// ---------------- output aggregation + bias + log_softmax (40 feats, 1 head) ----------------
__global__ void k_agg40(const float* __restrict__ H2, const float* __restrict__ ALs,
                        const float* __restrict__ ALd, const int* __restrict__ offs,
                        const int* __restrict__ csr, const float* __restrict__ b2,
                        float* __restrict__ out, int n){
  int node = blockIdx.x*16 + (threadIdx.x >> 4);
  int lane = threadIdx.x & 15;
  if (node >= n) return;
  int beg = offs[node], end = offs[node+1];
  float ald = ALd[node];
  float mx = -1e30f;
  for (int e = beg + lane; e < end; e += 16){
    int s = csr[e];
    mx = fmaxf(mx, lrelu(ALs[s] + ald));
  }
  mx = fmaxf(mx, __shfl_xor(mx,1));
  mx = fmaxf(mx, __shfl_xor(mx,2));
  mx = fmaxf(mx, __shfl_xor(mx,4));
  mx = fmaxf(mx, __shfl_xor(mx,8));
  bool act = lane < 10;
  int c = lane*4;
  float4 acc = make_float4(0.f,0.f,0.f,0.f);
  float wsum = 0.f;
  for (int e = beg; e < end; ++e){
    int s = csr[e];
    float w = __expf(lrelu(ALs[s] + ald) - mx);
    wsum += w;
    if (act){
      float4 hv = *(const float4*)(H2 + (size_t)s*40 + c);
      acc.x = fmaf(w, hv.x, acc.x);
      acc.y = fmaf(w, hv.y, acc.y);
      acc.z = fmaf(w, hv.z, acc.z);
      acc.w = fmaf(w, hv.w, acc.w);
    }
  }
  float inv = 1.f / wsum;
  float y0=0.f, y1=0.f, y2=0.f, y3=0.f;
  if (act){
    float4 b4 = *(const float4*)(b2 + c);
    y0 = acc.x*inv + b4.x;
    y1 = acc.y*inv + b4.y;
    y2 = acc.z*inv + b4.z;
    y3 = acc.w*inv + b4.w;
  }
  float lm = act ? fmaxf(fmaxf(y0,y1), fmaxf(y2,y3)) : -1e30f;
  lm = fmaxf(lm, __shfl_xor(lm,1));
  lm = fmaxf(lm, __shfl_xor(lm,2));
  lm = fmaxf(lm, __shfl_xor(lm,4));
  lm = fmaxf(lm, __shfl_xor(lm,8));
  float ls = act ? (__expf(y0-lm)+__expf(y1-lm)+__expf(y2-lm)+__expf(y3-lm)) : 0.f;
  ls += __shfl_xor(ls,1);
  ls += __shfl_xor(ls,2);
  ls += __shfl_xor(ls,4);
  ls += __shfl_xor(ls,8);
  float lg = lm + __logf(ls);
  if (act)
    *(float4*)(out + (size_t)node*40 + c) = make_float4(y0-lg, y1-lg, y2-lg, y3-lg);
}

extern "C" void kernel_launch(void* const* d_in, const int* in_sizes, int n_in,
                              void* d_out, int out_size, void* d_ws, size_t ws_size,
                              hipStream_t stream) {
  const float* x   = (const float*)d_in[0];
  const int*   ei  = (const int*)d_in[1];
  const float* W0  = (const float*)d_in[2];
  const float* as0 = (const float*)d_in[3];
  const float* ad0 = (const float*)d_in[4];
  const float* b0  = (const float*)d_in[5];
  const float* g0  = (const float*)d_in[6];
  const float* be0 = (const float*)d_in[7];
  const float* m0  = (const float*)d_in[8];
  const float* v0  = (const float*)d_in[9];
  const float* W1  = (const float*)d_in[10];
  const float* as1 = (const float*)d_in[11];
  const float* ad1 = (const float*)d_in[12];
  const float* b1  = (const float*)d_in[13];
  const float* g1  = (const float*)d_in[14];
  const float* be1 = (const float*)d_in[15];
  const float* m1  = (const float*)d_in[16];
  const float* v1  = (const float*)d_in[17];
  const float* W2  = (const float*)d_in[18];
  const float* as2 = (const float*)d_in[19];
  const float* ad2 = (const float*)d_in[20];
  const float* b2  = (const float*)d_in[21];
  float* out = (float*)d_out;

  int N = in_sizes[0] / 128;
  int E = in_sizes[1] / 2;
  int ET = E + N;

  char* p = (char*)d_ws;
  auto alloc = [&](size_t bytes)->void* {
    void* r = (void*)p;
    p += (bytes + 255) & ~size_t(255);
    return r;
  };
  float* Wt0 = (float*)alloc((size_t)128*128*4);
  float* Wt1 = (float*)alloc((size_t)128*128*4);
  float* Wt2 = (float*)alloc((size_t)128*40*4);
  int* deg     = (int*)alloc((size_t)N*4);
  int* cursor  = (int*)alloc((size_t)N*4);
  int* offs    = (int*)alloc((size_t)(N+1)*4);
  int* partials= (int*)alloc(1024*4);
  int* csr     = (int*)alloc((size_t)ET*4);
  float* P   = (float*)alloc((size_t)N*128*4);
  float* G   = (float*)alloc((size_t)N*128*4);
  float* ALs = (float*)alloc((size_t)N*4*4);
  float* ALd = (float*)alloc((size_t)N*4*4);
  float* H2   = P;     // P free by the time layer-2 GEMM runs
  float* al2s = ALs;
  float* al2d = ALd;
  if ((size_t)(p - (char*)d_ws) > ws_size) return;  // workspace too small

  hipMemsetAsync(deg, 0, (size_t)N*4, stream);
  hipMemsetAsync(cursor, 0, (size_t)N*4, stream);

  // transpose weights
  k_transpose<<<(128*128+255)/256, 256, 0, stream>>>(W0, Wt0, 128, 128);
  k_transpose<<<(128*128+255)/256, 256, 0, stream>>>(W1, Wt1, 128, 128);
  k_transpose<<<(40*128+255)/256, 256, 0, stream>>>(W2, Wt2, 40, 128);

  // CSR build (dst-sorted)
  int nb_scan = (N + 1023) / 1024;
  k_deg<<<(ET+255)/256, 256, 0, stream>>>(ei, E, N, deg);
  k_scan1<<<nb_scan, 256, 0, stream>>>(deg, offs+1, partials, N);
  k_scan2<<<1, 256, 0, stream>>>(partials, nb_scan);
  k_scan3<<<(N+255)/256, 256, 0, stream>>>(offs, partials, N);
  k_scatter<<<(ET+255)/256, 256, 0, stream>>>(ei, E, N, offs, cursor, csr);

  // ---- layer 0 ----
  k_gemm128<<<(N+31)/32, 256, 0, stream>>>(x, Wt0, P, N);
  k_al<<<(N+7)/8, 256, 0, stream>>>(P, as0, ad0, ALs, ALd, N);
  k_agg128<<<(N+7)/8, 256, 0, stream>>>(P, ALs, ALd, offs, csr, b0, g0, be0, m0, v0, G, N);

  // ---- layer 1 ----
  k_gemm128<<<(N+31)/32, 256, 0, stream>>>(G, Wt1, P, N);
  k_al<<<(N+7)/8, 256, 0, stream>>>(P, as1, ad1, ALs, ALd, N);
  k_agg128<<<(N+7)/8, 256, 0, stream>>>(P, ALs, ALd, offs, csr, b1, g1, be1, m1, v1, G, N);

  // ---- output layer ----
  k_gemm40<<<(N+3)/4, 256, 0, stream>>>(G, Wt2, as2, ad2, H2, al2s, al2d, N);
  k_agg40<<<(N+15)/16, 256, 0, stream>>>(H2, al2s, al2d, offs, csr, b2, out, N);
}

// Round 2
// 867.986 us; speedup vs baseline: 1.1529x; 1.1529x over previous
//
#include <hip/hip_runtime.h>
#include <math.h>

#define NEGS 0.2f
#define EPSBN 1e-5f

static __device__ __forceinline__ float lrelu(float x){ return x > 0.f ? x : NEGS*x; }

// ---------------- transpose W [R][C] -> Wt [C][R] ----------------
__global__ void k_transpose(const float* __restrict__ in, float* __restrict__ out, int R, int C){
  int i = blockIdx.x*256 + threadIdx.x;
  if (i >= R*C) return;
  int r = i / C, c = i - r*C;
  out[c*R + r] = in[i];
}

// pad+transpose W2 [40][128] -> Wt2p [128][64] (cols >=40 zero)
__global__ void k_padW2(const float* __restrict__ W2, float* __restrict__ Wt2p){
  int i = blockIdx.x*256 + threadIdx.x;
  if (i >= 128*64) return;
  int k = i >> 6, c = i & 63;
  Wt2p[i] = (c < 40) ? W2[c*128 + k] : 0.f;
}

// ---------------- CSR build ----------------
__global__ void k_deg(const int* __restrict__ ei, int E, int N, int* __restrict__ deg){
  int i = blockIdx.x*256 + threadIdx.x;
  if (i >= E + N) return;
  int d = (i < E) ? ei[E + i] : (i - E);
  atomicAdd(&deg[d], 1);
}

__global__ void k_scan1(const int* __restrict__ deg, int* __restrict__ incl,
                        int* __restrict__ partials, int n){
  __shared__ int sd[256];
  int tid = threadIdx.x;
  int base = blockIdx.x*1024 + tid*4;
  int v[4]; int s = 0;
  #pragma unroll
  for (int j=0;j<4;++j){ int idx = base+j; v[j] = (idx<n)? deg[idx] : 0; s += v[j]; }
  sd[tid] = s; __syncthreads();
  for (int off=1; off<256; off<<=1){
    int t = (tid>=off)? sd[tid-off] : 0;
    __syncthreads();
    sd[tid] += t;
    __syncthreads();
  }
  int run = sd[tid] - s;
  #pragma unroll
  for (int j=0;j<4;++j){ int idx = base+j; run += v[j]; if (idx<n) incl[idx] = run; }
  if (tid==255) partials[blockIdx.x] = sd[255];
}

__global__ void k_scan2(int* partials, int nb){
  __shared__ int sd[256];
  int tid = threadIdx.x;
  sd[tid] = (tid<nb)? partials[tid] : 0;
  __syncthreads();
  for (int off=1; off<256; off<<=1){
    int t = (tid>=off)? sd[tid-off] : 0;
    __syncthreads();
    sd[tid] += t;
    __syncthreads();
  }
  if (tid<nb) partials[tid] = sd[tid];
}

__global__ void k_scan3(int* __restrict__ offs, const int* __restrict__ partials, int n){
  int i = blockIdx.x*256 + threadIdx.x;
  if (i == 0) offs[0] = 0;
  if (i >= n) return;
  int b = i >> 10;
  if (b > 0) offs[i+1] += partials[b-1];
}

__global__ void k_scatter(const int* __restrict__ ei, int E, int N,
                          const int* __restrict__ offs, int* __restrict__ cursor,
                          int* __restrict__ csr){
  int i = blockIdx.x*256 + threadIdx.x;
  if (i >= E + N) return;
  int s, d;
  if (i < E){ s = ei[i]; d = ei[E+i]; } else { s = i - E; d = i - E; }
  int pos = offs[d] + atomicAdd(&cursor[d], 1);
  csr[pos] = s;
}

// ------- GEMM 128x128 + fused attention-logit epilogue -------
// Y[n][o] = sum_k X[n][k]*Wt[k][o]; ALs[n][h]=sum_c Y[n][h*32+c]*as[h][c] (same ALd)
__global__ __launch_bounds__(256) void k_gemm128(const float* __restrict__ X,
                                                 const float* __restrict__ Wt,
                                                 const float* __restrict__ as_,
                                                 const float* __restrict__ ad_,
                                                 float* __restrict__ Y,
                                                 float* __restrict__ ALs,
                                                 float* __restrict__ ALd, int n){
  __shared__ float xt[128*36];   // xt[k*36 + r], r in [0,32)
  int tid = threadIdx.x;
  int r0 = blockIdx.x * 32;
  {
    // conflict-free staging: r = lane, k wave-uniform per inner op
    int r  = tid & 31;
    int c0 = (tid >> 5) * 16;
    int row = r0 + r;
    const float4* src = (const float4*)(X + (size_t)row*128 + c0);
    #pragma unroll
    for (int j=0;j<4;++j){
      float4 v = (row < n) ? src[j] : make_float4(0.f,0.f,0.f,0.f);
      int k = c0 + j*4;
      xt[(k+0)*36 + r] = v.x;
      xt[(k+1)*36 + r] = v.y;
      xt[(k+2)*36 + r] = v.z;
      xt[(k+3)*36 + r] = v.w;
    }
  }
  __syncthreads();
  int tc = tid & 31, tr = tid >> 5;
  float acc[4][4] = {};
  #pragma unroll 4
  for (int k=0;k<128;++k){
    float4 wv = *(const float4*)(Wt + k*128 + tc*4);
    float4 xv = *(const float4*)(&xt[k*36 + tr*4]);
    float xv4[4] = {xv.x, xv.y, xv.z, xv.w};
    float wv4[4] = {wv.x, wv.y, wv.z, wv.w};
    #pragma unroll
    for (int u=0;u<4;++u)
      #pragma unroll
      for (int v=0;v<4;++v)
        acc[u][v] = fmaf(xv4[u], wv4[v], acc[u][v]);
  }
  // store Y
  #pragma unroll
  for (int u=0;u<4;++u){
    int row = r0 + tr*4 + u;
    if (row < n)
      *(float4*)(Y + (size_t)row*128 + tc*4) =
        make_float4(acc[u][0], acc[u][1], acc[u][2], acc[u][3]);
  }
  // fused attention logits: head = tc>>3, cols-in-head (tc&7)*4 + j
  int hd = tc >> 3;
  float4 a4 = *(const float4*)(as_ + hd*32 + (tc&7)*4);
  float4 d4 = *(const float4*)(ad_ + hd*32 + (tc&7)*4);
  #pragma unroll
  for (int u=0;u<4;++u){
    float ps = acc[u][0]*a4.x + acc[u][1]*a4.y + acc[u][2]*a4.z + acc[u][3]*a4.w;
    float pd = acc[u][0]*d4.x + acc[u][1]*d4.y + acc[u][2]*d4.z + acc[u][3]*d4.w;
    ps += __shfl_xor(ps,1); ps += __shfl_xor(ps,2); ps += __shfl_xor(ps,4);
    pd += __shfl_xor(pd,1); pd += __shfl_xor(pd,2); pd += __shfl_xor(pd,4);
    int row = r0 + tr*4 + u;
    if ((tc&7)==0 && row < n){ ALs[row*4+hd] = ps; ALd[row*4+hd] = pd; }
  }
}

// ---------------- fused GAT aggregation + bias + BN + ReLU (128 feats, 4 heads) ----------------
__global__ void k_agg128(const float* __restrict__ H, const float* __restrict__ ALs,
                         const float* __restrict__ ALd, const int* __restrict__ offs,
                         const int* __restrict__ csr,
                         const float* __restrict__ bias, const float* __restrict__ gam,
                         const float* __restrict__ bet, const float* __restrict__ mean,
                         const float* __restrict__ var, float* __restrict__ out, int n){
  int node = blockIdx.x*8 + (threadIdx.x >> 5);
  int lane = threadIdx.x & 31;
  if (node >= n) return;
  int hd = lane >> 3;
  int beg = offs[node], end = offs[node+1];
  float4 ald4 = *(const float4*)(ALd + node*4);
  // phase 1: per-head segment max (lanes parallel over edges)
  float m0=-1e30f, m1=-1e30f, m2=-1e30f, m3=-1e30f;
  for (int e = beg + lane; e < end; e += 32){
    int s = csr[e];
    float4 a = *(const float4*)(ALs + s*4);
    m0 = fmaxf(m0, lrelu(a.x + ald4.x));
    m1 = fmaxf(m1, lrelu(a.y + ald4.y));
    m2 = fmaxf(m2, lrelu(a.z + ald4.z));
    m3 = fmaxf(m3, lrelu(a.w + ald4.w));
  }
  #pragma unroll
  for (int off=1; off<32; off<<=1){
    m0 = fmaxf(m0, __shfl_xor(m0, off));
    m1 = fmaxf(m1, __shfl_xor(m1, off));
    m2 = fmaxf(m2, __shfl_xor(m2, off));
    m3 = fmaxf(m3, __shfl_xor(m3, off));
  }
  float mh   = (hd==0) ? m0 : (hd==1) ? m1 : (hd==2) ? m2 : m3;
  float aldh = (hd==0) ? ald4.x : (hd==1) ? ald4.y : (hd==2) ? ald4.z : ald4.w;
  // phase 2: serial over edges, lanes parallel over features
  float4 acc = make_float4(0.f,0.f,0.f,0.f);
  float wsum = 0.f;
  for (int e = beg; e < end; ++e){
    int s = csr[e];
    float als = ALs[s*4 + hd];
    float w = __expf(lrelu(als + aldh) - mh);
    wsum += w;
    float4 hv = *(const float4*)(H + (size_t)s*128 + lane*4);
    acc.x = fmaf(w, hv.x, acc.x);
    acc.y = fmaf(w, hv.y, acc.y);
    acc.z = fmaf(w, hv.z, acc.z);
    acc.w = fmaf(w, hv.w, acc.w);
  }
  float inv = 1.f / wsum;
  int c = lane*4;
  float4 b4 = *(const float4*)(bias+c);
  float4 g4 = *(const float4*)(gam+c);
  float4 e4 = *(const float4*)(bet+c);
  float4 u4 = *(const float4*)(mean+c);
  float4 v4 = *(const float4*)(var+c);
  float o0 = (acc.x*inv + b4.x - u4.x) * rsqrtf(v4.x + EPSBN) * g4.x + e4.x;
  float o1 = (acc.y*inv + b4.y - u4.y) * rsqrtf(v4.y + EPSBN) * g4.y + e4.y;
  float o2 = (acc.z*inv + b4.z - u4.z) * rsqrtf(v4.z + EPSBN) * g4.z + e4.z;
  float o3 = (acc.w*inv + b4.w - u4.w) * rsqrtf(v4.w + EPSBN) * g4.w + e4.w;
  *(float4*)(out + (size_t)node*128 + c) =
      make_float4(fmaxf(o0,0.f), fmaxf(o1,0.f), fmaxf(o2,0.f), fmaxf(o3,0.f));
}

// ------- output layer GEMM (128->40, padded 64) + fused attention logits -------
__global__ __launch_bounds__(256) void k_gemm40n(const float* __restrict__ X,
                                                 const float* __restrict__ Wt2p,
                                                 const float* __restrict__ as2,
                                                 const float* __restrict__ ad2,
                                                 float* __restrict__ H2,
                                                 float* __restrict__ al2s,
                                                 float* __restrict__ al2d, int n){
  __shared__ float xt[128*68];   // xt[k*68 + r], r in [0,64)
  int tid = threadIdx.x;
  int r0 = blockIdx.x * 64;
  {
    int r  = tid & 63;
    int c0 = (tid >> 6) * 32;   // 4 waves cover 128 cols
    int row = r0 + r;
    const float4* src = (const float4*)(X + (size_t)row*128 + c0);
    #pragma unroll
    for (int j=0;j<8;++j){
      float4 v = (row < n) ? src[j] : make_float4(0.f,0.f,0.f,0.f);
      int k = c0 + j*4;
      xt[(k+0)*68 + r] = v.x;
      xt[(k+1)*68 + r] = v.y;
      xt[(k+2)*68 + r] = v.z;
      xt[(k+3)*68 + r] = v.w;
    }
  }
  __syncthreads();
  int tc = tid & 15, tr = tid >> 4;   // 16 colgroups x 16 rowgroups
  float acc[4][4] = {};
  #pragma unroll 4
  for (int k=0;k<128;++k){
    float4 wv = *(const float4*)(Wt2p + k*64 + tc*4);
    float4 xv = *(const float4*)(&xt[k*68 + tr*4]);
    float xv4[4] = {xv.x, xv.y, xv.z, xv.w};
    float wv4[4] = {wv.x, wv.y, wv.z, wv.w};
    #pragma unroll
    for (int u=0;u<4;++u)
      #pragma unroll
      for (int v=0;v<4;++v)
        acc[u][v] = fmaf(xv4[u], wv4[v], acc[u][v]);
  }
  // epilogue: store H2 (cols<40) + attention logits over 40 cols
  float4 a4 = make_float4(0.f,0.f,0.f,0.f), d4 = a4;
  if (tc < 10){
    a4 = *(const float4*)(as2 + tc*4);
    d4 = *(const float4*)(ad2 + tc*4);
  }
  #pragma unroll
  for (int u=0;u<4;++u){
    int row = r0 + tr*4 + u;
    float ps = acc[u][0]*a4.x + acc[u][1]*a4.y + acc[u][2]*a4.z + acc[u][3]*a4.w;
    float pd = acc[u][0]*d4.x + acc[u][1]*d4.y + acc[u][2]*d4.z + acc[u][3]*d4.w;
    #pragma unroll
    for (int m=1; m<16; m<<=1){ ps += __shfl_xor(ps,m); pd += __shfl_xor(pd,m); }
    if (row < n){
      if (tc < 10)
        *(float4*)(H2 + (size_t)row*40 + tc*4) =
          make_float4(acc[u][0], acc[u][1], acc[u][2], acc[u][3]);
      if (tc == 0){ al2s[row] = ps; al2d[row] = pd; }
    }
  }
}

// ---------------- output aggregation + bias + log_softmax (40 feats, 1 head) ----------------
__global__ void k_agg40(const float* __restrict__ H2, const float* __restrict__ ALs,
                        const float* __restrict__ ALd, const int* __restrict__ offs,
                        const int* __restrict__ csr, const float* __restrict__ b2,
                        float* __restrict__ out, int n){
  int node = blockIdx.x*16 + (threadIdx.x >> 4);
  int lane = threadIdx.x & 15;
  if (node >= n) return;
  int beg = offs[node], end = offs[node+1];
  float ald = ALd[node];
  float mx = -1e30f;
  for (int e = beg + lane; e < end; e += 16){
    int s = csr[e];
    mx = fmaxf(mx, lrelu(ALs[s] + ald));
  }
  mx = fmaxf(mx, __shfl_xor(mx,1));
  mx = fmaxf(mx, __shfl_xor(mx,2));
  mx = fmaxf(mx, __shfl_xor(mx,4));
  mx = fmaxf(mx, __shfl_xor(mx,8));
  bool act = lane < 10;
  int c = lane*4;
  float4 acc = make_float4(0.f,0.f,0.f,0.f);
  float wsum = 0.f;
  for (int e = beg; e < end; ++e){
    int s = csr[e];
    float w = __expf(lrelu(ALs[s] + ald) - mx);
    wsum += w;
    if (act){
      float4 hv = *(const float4*)(H2 + (size_t)s*40 + c);
      acc.x = fmaf(w, hv.x, acc.x);
      acc.y = fmaf(w, hv.y, acc.y);
      acc.z = fmaf(w, hv.z, acc.z);
      acc.w = fmaf(w, hv.w, acc.w);
    }
  }
  float inv = 1.f / wsum;
  float y0=0.f, y1=0.f, y2=0.f, y3=0.f;
  if (act){
    float4 b4 = *(const float4*)(b2 + c);
    y0 = acc.x*inv + b4.x;
    y1 = acc.y*inv + b4.y;
    y2 = acc.z*inv + b4.z;
    y3 = acc.w*inv + b4.w;
  }
  float lm = act ? fmaxf(fmaxf(y0,y1), fmaxf(y2,y3)) : -1e30f;
  lm = fmaxf(lm, __shfl_xor(lm,1));
  lm = fmaxf(lm, __shfl_xor(lm,2));
  lm = fmaxf(lm, __shfl_xor(lm,4));
  lm = fmaxf(lm, __shfl_xor(lm,8));
  float ls = act ? (__expf(y0-lm)+__expf(y1-lm)+__expf(y2-lm)+__expf(y3-lm)) : 0.f;
  ls += __shfl_xor(ls,1);
  ls += __shfl_xor(ls,2);
  ls += __shfl_xor(ls,4);
  ls += __shfl_xor(ls,8);
  float lg = lm + __logf(ls);
  if (act)
    *(float4*)(out + (size_t)node*40 + c) = make_float4(y0-lg, y1-lg, y2-lg, y3-lg);
}

extern "C" void kernel_launch(void* const* d_in, const int* in_sizes, int n_in,
                              void* d_out, int out_size, void* d_ws, size_t ws_size,
                              hipStream_t stream) {
  const float* x   = (const float*)d_in[0];
  const int*   ei  = (const int*)d_in[1];
  const float* W0  = (const float*)d_in[2];
  const float* as0 = (const float*)d_in[3];
  const float* ad0 = (const float*)d_in[4];
  const float* b0  = (const float*)d_in[5];
  const float* g0  = (const float*)d_in[6];
  const float* be0 = (const float*)d_in[7];
  const float* m0  = (const float*)d_in[8];
  const float* v0  = (const float*)d_in[9];
  const float* W1  = (const float*)d_in[10];
  const float* as1 = (const float*)d_in[11];
  const float* ad1 = (const float*)d_in[12];
  const float* b1  = (const float*)d_in[13];
  const float* g1  = (const float*)d_in[14];
  const float* be1 = (const float*)d_in[15];
  const float* m1  = (const float*)d_in[16];
  const float* v1  = (const float*)d_in[17];
  const float* W2  = (const float*)d_in[18];
  const float* as2 = (const float*)d_in[19];
  const float* ad2 = (const float*)d_in[20];
  const float* b2  = (const float*)d_in[21];
  float* out = (float*)d_out;

  int N = in_sizes[0] / 128;
  int E = in_sizes[1] / 2;
  int ET = E + N;

  char* p = (char*)d_ws;
  auto alloc = [&](size_t bytes)->void* {
    void* r = (void*)p;
    p += (bytes + 255) & ~size_t(255);
    return r;
  };
  float* Wt0 = (float*)alloc((size_t)128*128*4);
  float* Wt1 = (float*)alloc((size_t)128*128*4);
  float* Wt2p= (float*)alloc((size_t)128*64*4);
  int* deg     = (int*)alloc((size_t)N*4);
  int* cursor  = (int*)alloc((size_t)N*4);
  int* offs    = (int*)alloc((size_t)(N+1)*4);
  int* partials= (int*)alloc(1024*4);
  int* csr     = (int*)alloc((size_t)ET*4);
  float* P   = (float*)alloc((size_t)N*128*4);
  float* G   = (float*)alloc((size_t)N*128*4);
  float* ALs = (float*)alloc((size_t)N*4*4);
  float* ALd = (float*)alloc((size_t)N*4*4);
  float* H2   = P;     // P free by the time layer-2 GEMM runs
  float* al2s = ALs;
  float* al2d = ALd;
  if ((size_t)(p - (char*)d_ws) > ws_size) return;  // workspace too small

  hipMemsetAsync(deg, 0, (size_t)N*4, stream);
  hipMemsetAsync(cursor, 0, (size_t)N*4, stream);

  // weight prep
  k_transpose<<<(128*128+255)/256, 256, 0, stream>>>(W0, Wt0, 128, 128);
  k_transpose<<<(128*128+255)/256, 256, 0, stream>>>(W1, Wt1, 128, 128);
  k_padW2<<<(128*64+255)/256, 256, 0, stream>>>(W2, Wt2p);

  // CSR build (dst-sorted)
  int nb_scan = (N + 1023) / 1024;
  k_deg<<<(ET+255)/256, 256, 0, stream>>>(ei, E, N, deg);
  k_scan1<<<nb_scan, 256, 0, stream>>>(deg, offs+1, partials, N);
  k_scan2<<<1, 256, 0, stream>>>(partials, nb_scan);
  k_scan3<<<(N+255)/256, 256, 0, stream>>>(offs, partials, N);
  k_scatter<<<(ET+255)/256, 256, 0, stream>>>(ei, E, N, offs, cursor, csr);

  // ---- layer 0 ----
  k_gemm128<<<(N+31)/32, 256, 0, stream>>>(x, Wt0, as0, ad0, P, ALs, ALd, N);
  k_agg128<<<(N+7)/8, 256, 0, stream>>>(P, ALs, ALd, offs, csr, b0, g0, be0, m0, v0, G, N);

  // ---- layer 1 ----
  k_gemm128<<<(N+31)/32, 256, 0, stream>>>(G, Wt1, as1, ad1, P, ALs, ALd, N);
  k_agg128<<<(N+7)/8, 256, 0, stream>>>(P, ALs, ALd, offs, csr, b1, g1, be1, m1, v1, G, N);

  // ---- output layer ----
  k_gemm40n<<<(N+63)/64, 256, 0, stream>>>(G, Wt2p, as2, ad2, H2, al2s, al2d, N);
  k_agg40<<<(N+15)/16, 256, 0, stream>>>(H2, al2s, al2d, offs, csr, b2, out, N);
}

// Round 3
// 788.971 us; speedup vs baseline: 1.2684x; 1.1001x over previous
//
#include <hip/hip_runtime.h>
#include <math.h>

#define NEGS 0.2f
#define EPSBN 1e-5f

static __device__ __forceinline__ float lrelu(float x){ return x > 0.f ? x : NEGS*x; }
static __device__ __forceinline__ float bf2f(unsigned short v){
  return __uint_as_float(((unsigned)v) << 16);
}
static __device__ __forceinline__ unsigned short f2bf(float f){
  unsigned u = __float_as_uint(f);
  unsigned r = (u + 0x7fff + ((u >> 16) & 1)) >> 16;   // RNE
  return (unsigned short)r;
}

// ---------------- transpose W [R][C] -> Wt [C][R] ----------------
__global__ void k_transpose(const float* __restrict__ in, float* __restrict__ out, int R, int C){
  int i = blockIdx.x*256 + threadIdx.x;
  if (i >= R*C) return;
  int r = i / C, c = i - r*C;
  out[c*R + r] = in[i];
}

// pad+transpose W2 [40][128] -> Wt2p [128][64] (cols >=40 zero)
__global__ void k_padW2(const float* __restrict__ W2, float* __restrict__ Wt2p){
  int i = blockIdx.x*256 + threadIdx.x;
  if (i >= 128*64) return;
  int k = i >> 6, c = i & 63;
  Wt2p[i] = (c < 40) ? W2[c*128 + k] : 0.f;
}

// ---------------- CSR build ----------------
__global__ void k_deg(const int* __restrict__ ei, int E, int N, int* __restrict__ deg){
  int i = blockIdx.x*256 + threadIdx.x;
  if (i >= E + N) return;
  int d = (i < E) ? ei[E + i] : (i - E);
  atomicAdd(&deg[d], 1);
}

__global__ void k_scan1(const int* __restrict__ deg, int* __restrict__ incl,
                        int* __restrict__ partials, int n){
  __shared__ int sd[256];
  int tid = threadIdx.x;
  int base = blockIdx.x*1024 + tid*4;
  int v[4]; int s = 0;
  #pragma unroll
  for (int j=0;j<4;++j){ int idx = base+j; v[j] = (idx<n)? deg[idx] : 0; s += v[j]; }
  sd[tid] = s; __syncthreads();
  for (int off=1; off<256; off<<=1){
    int t = (tid>=off)? sd[tid-off] : 0;
    __syncthreads();
    sd[tid] += t;
    __syncthreads();
  }
  int run = sd[tid] - s;
  #pragma unroll
  for (int j=0;j<4;++j){ int idx = base+j; run += v[j]; if (idx<n) incl[idx] = run; }
  if (tid==255) partials[blockIdx.x] = sd[255];
}

__global__ void k_scan2(int* partials, int nb){
  __shared__ int sd[256];
  int tid = threadIdx.x;
  sd[tid] = (tid<nb)? partials[tid] : 0;
  __syncthreads();
  for (int off=1; off<256; off<<=1){
    int t = (tid>=off)? sd[tid-off] : 0;
    __syncthreads();
    sd[tid] += t;
    __syncthreads();
  }
  if (tid<nb) partials[tid] = sd[tid];
}

__global__ void k_scan3(int* __restrict__ offs, const int* __restrict__ partials, int n){
  int i = blockIdx.x*256 + threadIdx.x;
  if (i == 0) offs[0] = 0;
  if (i >= n) return;
  int b = i >> 10;
  if (b > 0) offs[i+1] += partials[b-1];
}

__global__ void k_scatter(const int* __restrict__ ei, int E, int N,
                          const int* __restrict__ offs, int* __restrict__ cursor,
                          int* __restrict__ csr){
  int i = blockIdx.x*256 + threadIdx.x;
  if (i >= E + N) return;
  int s, d;
  if (i < E){ s = ei[i]; d = ei[E+i]; } else { s = i - E; d = i - E; }
  int pos = offs[d] + atomicAdd(&cursor[d], 1);
  csr[pos] = s;
}

// ------- GEMM 128x128 (f32 in, bf16 out) + fused attention-logit epilogue -------
__global__ __launch_bounds__(256) void k_gemm128(const float* __restrict__ X,
                                                 const float* __restrict__ Wt,
                                                 const float* __restrict__ as_,
                                                 const float* __restrict__ ad_,
                                                 unsigned short* __restrict__ Yb,
                                                 float* __restrict__ ALs,
                                                 float* __restrict__ ALd, int n){
  __shared__ float xt[128*36];   // xt[k*36 + r], r in [0,32)
  int tid = threadIdx.x;
  int r0 = blockIdx.x * 32;
  {
    int r  = tid & 31;
    int c0 = (tid >> 5) * 16;
    int row = r0 + r;
    const float4* src = (const float4*)(X + (size_t)row*128 + c0);
    #pragma unroll
    for (int j=0;j<4;++j){
      float4 v = (row < n) ? src[j] : make_float4(0.f,0.f,0.f,0.f);
      int k = c0 + j*4;
      xt[(k+0)*36 + r] = v.x;
      xt[(k+1)*36 + r] = v.y;
      xt[(k+2)*36 + r] = v.z;
      xt[(k+3)*36 + r] = v.w;
    }
  }
  __syncthreads();
  int tc = tid & 31, tr = tid >> 5;
  float acc[4][4] = {};
  #pragma unroll 4
  for (int k=0;k<128;++k){
    float4 wv = *(const float4*)(Wt + k*128 + tc*4);
    float4 xv = *(const float4*)(&xt[k*36 + tr*4]);
    float xv4[4] = {xv.x, xv.y, xv.z, xv.w};
    float wv4[4] = {wv.x, wv.y, wv.z, wv.w};
    #pragma unroll
    for (int u=0;u<4;++u)
      #pragma unroll
      for (int v=0;v<4;++v)
        acc[u][v] = fmaf(xv4[u], wv4[v], acc[u][v]);
  }
  // store Y as bf16 (consumed only by the aggregation gather)
  #pragma unroll
  for (int u=0;u<4;++u){
    int row = r0 + tr*4 + u;
    if (row < n){
      ushort4 o;
      o.x = f2bf(acc[u][0]); o.y = f2bf(acc[u][1]);
      o.z = f2bf(acc[u][2]); o.w = f2bf(acc[u][3]);
      *(ushort4*)(Yb + (size_t)row*128 + tc*4) = o;
    }
  }
  // fused attention logits
  int hd = tc >> 3;
  float4 a4 = *(const float4*)(as_ + hd*32 + (tc&7)*4);
  float4 d4 = *(const float4*)(ad_ + hd*32 + (tc&7)*4);
  #pragma unroll
  for (int u=0;u<4;++u){
    float ps = acc[u][0]*a4.x + acc[u][1]*a4.y + acc[u][2]*a4.z + acc[u][3]*a4.w;
    float pd = acc[u][0]*d4.x + acc[u][1]*d4.y + acc[u][2]*d4.z + acc[u][3]*d4.w;
    ps += __shfl_xor(ps,1); ps += __shfl_xor(ps,2); ps += __shfl_xor(ps,4);
    pd += __shfl_xor(pd,1); pd += __shfl_xor(pd,2); pd += __shfl_xor(pd,4);
    int row = r0 + tr*4 + u;
    if ((tc&7)==0 && row < n){ ALs[row*4+hd] = ps; ALd[row*4+hd] = pd; }
  }
}

// ------- fused GAT aggregation + bias + BN + ReLU (bf16 gather, no max pass) -------
// one wave (64 lanes) per node; lanes 0-31 even edges, 32-63 odd edges
__global__ __launch_bounds__(256) void k_agg128b(const unsigned short* __restrict__ Pb,
                         const float* __restrict__ ALs, const float* __restrict__ ALd,
                         const int* __restrict__ offs, const int* __restrict__ csr,
                         const float* __restrict__ bias, const float* __restrict__ gam,
                         const float* __restrict__ bet, const float* __restrict__ mean,
                         const float* __restrict__ var, float* __restrict__ out, int n){
  int node = blockIdx.x*4 + (threadIdx.x >> 6);
  int lane = threadIdx.x & 63;
  if (node >= n) return;
  int half = lane >> 5, fl = lane & 31, hd = fl >> 3;
  int beg = offs[node], end = offs[node+1];
  int deg = end - beg;
  float aldh = ALd[node*4 + hd];
  int c = (lane < deg) ? csr[beg + lane] : 0;   // preload up to 64 edge indices
  float4 acc = make_float4(0.f,0.f,0.f,0.f);
  float wsum = 0.f;
  int nsteps = (deg + 1) >> 1;
  #pragma unroll 2
  for (int t = 0; t < nsteps; ++t){
    int idx = 2*t + half;
    bool valid = idx < deg;
    int s = (idx < 64) ? __shfl(c, idx) : (valid ? csr[beg + idx] : 0);
    float als = ALs[s*4 + hd];
    float w = valid ? __expf(lrelu(als + aldh)) : 0.f;
    wsum += w;
    ushort4 hv = *(const ushort4*)(Pb + (size_t)s*128 + fl*4);
    acc.x = fmaf(w, bf2f(hv.x), acc.x);
    acc.y = fmaf(w, bf2f(hv.y), acc.y);
    acc.z = fmaf(w, bf2f(hv.z), acc.z);
    acc.w = fmaf(w, bf2f(hv.w), acc.w);
  }
  acc.x += __shfl_xor(acc.x, 32);
  acc.y += __shfl_xor(acc.y, 32);
  acc.z += __shfl_xor(acc.z, 32);
  acc.w += __shfl_xor(acc.w, 32);
  wsum  += __shfl_xor(wsum, 32);
  if (half == 0){
    float inv = 1.f / wsum;
    int cc = fl*4;
    float4 b4 = *(const float4*)(bias+cc);
    float4 g4 = *(const float4*)(gam+cc);
    float4 e4 = *(const float4*)(bet+cc);
    float4 u4 = *(const float4*)(mean+cc);
    float4 v4 = *(const float4*)(var+cc);
    float o0 = (acc.x*inv + b4.x - u4.x) * rsqrtf(v4.x + EPSBN) * g4.x + e4.x;
    float o1 = (acc.y*inv + b4.y - u4.y) * rsqrtf(v4.y + EPSBN) * g4.y + e4.y;
    float o2 = (acc.z*inv + b4.z - u4.z) * rsqrtf(v4.z + EPSBN) * g4.z + e4.z;
    float o3 = (acc.w*inv + b4.w - u4.w) * rsqrtf(v4.w + EPSBN) * g4.w + e4.w;
    *(float4*)(out + (size_t)node*128 + cc) =
        make_float4(fmaxf(o0,0.f), fmaxf(o1,0.f), fmaxf(o2,0.f), fmaxf(o3,0.f));
  }
}

// ------- output layer GEMM (128->40, padded 64, bf16 H2 out) + fused logits -------
__global__ __launch_bounds__(256) void k_gemm40n(const float* __restrict__ X,
                                                 const float* __restrict__ Wt2p,
                                                 const float* __restrict__ as2,
                                                 const float* __restrict__ ad2,
                                                 unsigned short* __restrict__ H2b,
                                                 float* __restrict__ al2s,
                                                 float* __restrict__ al2d, int n){
  __shared__ float xt[128*68];   // xt[k*68 + r], r in [0,64)
  int tid = threadIdx.x;
  int r0 = blockIdx.x * 64;
  {
    int r  = tid & 63;
    int c0 = (tid >> 6) * 32;
    int row = r0 + r;
    const float4* src = (const float4*)(X + (size_t)row*128 + c0);
    #pragma unroll
    for (int j=0;j<8;++j){
      float4 v = (row < n) ? src[j] : make_float4(0.f,0.f,0.f,0.f);
      int k = c0 + j*4;
      xt[(k+0)*68 + r] = v.x;
      xt[(k+1)*68 + r] = v.y;
      xt[(k+2)*68 + r] = v.z;
      xt[(k+3)*68 + r] = v.w;
    }
  }
  __syncthreads();
  int tc = tid & 15, tr = tid >> 4;
  float acc[4][4] = {};
  #pragma unroll 4
  for (int k=0;k<128;++k){
    float4 wv = *(const float4*)(Wt2p + k*64 + tc*4);
    float4 xv = *(const float4*)(&xt[k*68 + tr*4]);
    float xv4[4] = {xv.x, xv.y, xv.z, xv.w};
    float wv4[4] = {wv.x, wv.y, wv.z, wv.w};
    #pragma unroll
    for (int u=0;u<4;++u)
      #pragma unroll
      for (int v=0;v<4;++v)
        acc[u][v] = fmaf(xv4[u], wv4[v], acc[u][v]);
  }
  float4 a4 = make_float4(0.f,0.f,0.f,0.f), d4 = a4;
  if (tc < 10){
    a4 = *(const float4*)(as2 + tc*4);
    d4 = *(const float4*)(ad2 + tc*4);
  }
  #pragma unroll
  for (int u=0;u<4;++u){
    int row = r0 + tr*4 + u;
    float ps = acc[u][0]*a4.x + acc[u][1]*a4.y + acc[u][2]*a4.z + acc[u][3]*a4.w;
    float pd = acc[u][0]*d4.x + acc[u][1]*d4.y + acc[u][2]*d4.z + acc[u][3]*d4.w;
    #pragma unroll
    for (int m=1; m<16; m<<=1){ ps += __shfl_xor(ps,m); pd += __shfl_xor(pd,m); }
    if (row < n){
      if (tc < 10){
        ushort4 o;
        o.x = f2bf(acc[u][0]); o.y = f2bf(acc[u][1]);
        o.z = f2bf(acc[u][2]); o.w = f2bf(acc[u][3]);
        *(ushort4*)(H2b + (size_t)row*40 + tc*4) = o;
      }
      if (tc == 0){ al2s[row] = ps; al2d[row] = pd; }
    }
  }
}

// ------- output aggregation + bias + log_softmax (bf16 gather, no max pass) -------
// 32 lanes per node; lanes 0-15 even edges, 16-31 odd edges
__global__ __launch_bounds__(256) void k_agg40b(const unsigned short* __restrict__ H2b,
                        const float* __restrict__ ALs, const float* __restrict__ ALd,
                        const int* __restrict__ offs, const int* __restrict__ csr,
                        const float* __restrict__ b2, float* __restrict__ out, int n){
  int node = blockIdx.x*8 + (threadIdx.x >> 5);
  int l32 = threadIdx.x & 31;
  if (node >= n) return;
  int half = l32 >> 4, fl = l32 & 15;
  int beg = offs[node], end = offs[node+1];
  int deg = end - beg;
  float ald = ALd[node];
  int c = (l32 < deg) ? csr[beg + l32] : 0;
  bool act = fl < 10;
  float4 acc = make_float4(0.f,0.f,0.f,0.f);
  float wsum = 0.f;
  int nsteps = (deg + 1) >> 1;
  #pragma unroll 2
  for (int t = 0; t < nsteps; ++t){
    int idx = 2*t + half;
    bool valid = idx < deg;
    int s = (idx < 32) ? __shfl(c, idx, 32) : (valid ? csr[beg + idx] : 0);
    float w = valid ? __expf(lrelu(ALs[s] + ald)) : 0.f;
    wsum += w;
    if (act){
      ushort4 hv = *(const ushort4*)(H2b + (size_t)s*40 + fl*4);
      acc.x = fmaf(w, bf2f(hv.x), acc.x);
      acc.y = fmaf(w, bf2f(hv.y), acc.y);
      acc.z = fmaf(w, bf2f(hv.z), acc.z);
      acc.w = fmaf(w, bf2f(hv.w), acc.w);
    }
  }
  acc.x += __shfl_xor(acc.x, 16);
  acc.y += __shfl_xor(acc.y, 16);
  acc.z += __shfl_xor(acc.z, 16);
  acc.w += __shfl_xor(acc.w, 16);
  wsum  += __shfl_xor(wsum, 16);
  if (half == 0){
    float inv = 1.f / wsum;
    float y0=0.f, y1=0.f, y2=0.f, y3=0.f;
    if (act){
      float4 b4 = *(const float4*)(b2 + fl*4);
      y0 = acc.x*inv + b4.x;
      y1 = acc.y*inv + b4.y;
      y2 = acc.z*inv + b4.z;
      y3 = acc.w*inv + b4.w;
    }
    float lm = act ? fmaxf(fmaxf(y0,y1), fmaxf(y2,y3)) : -1e30f;
    lm = fmaxf(lm, __shfl_xor(lm,1));
    lm = fmaxf(lm, __shfl_xor(lm,2));
    lm = fmaxf(lm, __shfl_xor(lm,4));
    lm = fmaxf(lm, __shfl_xor(lm,8));
    float ls = act ? (__expf(y0-lm)+__expf(y1-lm)+__expf(y2-lm)+__expf(y3-lm)) : 0.f;
    ls += __shfl_xor(ls,1);
    ls += __shfl_xor(ls,2);
    ls += __shfl_xor(ls,4);
    ls += __shfl_xor(ls,8);
    float lg = lm + __logf(ls);
    if (act)
      *(float4*)(out + (size_t)node*40 + fl*4) = make_float4(y0-lg, y1-lg, y2-lg, y3-lg);
  }
}

extern "C" void kernel_launch(void* const* d_in, const int* in_sizes, int n_in,
                              void* d_out, int out_size, void* d_ws, size_t ws_size,
                              hipStream_t stream) {
  const float* x   = (const float*)d_in[0];
  const int*   ei  = (const int*)d_in[1];
  const float* W0  = (const float*)d_in[2];
  const float* as0 = (const float*)d_in[3];
  const float* ad0 = (const float*)d_in[4];
  const float* b0  = (const float*)d_in[5];
  const float* g0  = (const float*)d_in[6];
  const float* be0 = (const float*)d_in[7];
  const float* m0  = (const float*)d_in[8];
  const float* v0  = (const float*)d_in[9];
  const float* W1  = (const float*)d_in[10];
  const float* as1 = (const float*)d_in[11];
  const float* ad1 = (const float*)d_in[12];
  const float* b1  = (const float*)d_in[13];
  const float* g1  = (const float*)d_in[14];
  const float* be1 = (const float*)d_in[15];
  const float* m1  = (const float*)d_in[16];
  const float* v1  = (const float*)d_in[17];
  const float* W2  = (const float*)d_in[18];
  const float* as2 = (const float*)d_in[19];
  const float* ad2 = (const float*)d_in[20];
  const float* b2  = (const float*)d_in[21];
  float* out = (float*)d_out;

  int N = in_sizes[0] / 128;
  int E = in_sizes[1] / 2;
  int ET = E + N;

  char* p = (char*)d_ws;
  auto alloc = [&](size_t bytes)->void* {
    void* r = (void*)p;
    p += (bytes + 255) & ~size_t(255);
    return r;
  };
  float* Wt0 = (float*)alloc((size_t)128*128*4);
  float* Wt1 = (float*)alloc((size_t)128*128*4);
  float* Wt2p= (float*)alloc((size_t)128*64*4);
  int* deg     = (int*)alloc((size_t)N*4);
  int* cursor  = (int*)alloc((size_t)N*4);
  int* offs    = (int*)alloc((size_t)(N+1)*4);
  int* partials= (int*)alloc(1024*4);
  int* csr     = (int*)alloc((size_t)ET*4);
  unsigned short* Pb = (unsigned short*)alloc((size_t)N*128*2);
  float* G   = (float*)alloc((size_t)N*128*4);
  float* ALs = (float*)alloc((size_t)N*4*4);
  float* ALd = (float*)alloc((size_t)N*4*4);
  unsigned short* H2b = Pb;     // Pb free by the time layer-2 GEMM runs
  float* al2s = ALs;
  float* al2d = ALd;
  if ((size_t)(p - (char*)d_ws) > ws_size) return;  // workspace too small

  hipMemsetAsync(deg, 0, (size_t)N*4, stream);
  hipMemsetAsync(cursor, 0, (size_t)N*4, stream);

  // weight prep
  k_transpose<<<(128*128+255)/256, 256, 0, stream>>>(W0, Wt0, 128, 128);
  k_transpose<<<(128*128+255)/256, 256, 0, stream>>>(W1, Wt1, 128, 128);
  k_padW2<<<(128*64+255)/256, 256, 0, stream>>>(W2, Wt2p);

  // CSR build (dst-sorted)
  int nb_scan = (N + 1023) / 1024;
  k_deg<<<(ET+255)/256, 256, 0, stream>>>(ei, E, N, deg);
  k_scan1<<<nb_scan, 256, 0, stream>>>(deg, offs+1, partials, N);
  k_scan2<<<1, 256, 0, stream>>>(partials, nb_scan);
  k_scan3<<<(N+255)/256, 256, 0, stream>>>(offs, partials, N);
  k_scatter<<<(ET+255)/256, 256, 0, stream>>>(ei, E, N, offs, cursor, csr);

  // ---- layer 0 ----
  k_gemm128<<<(N+31)/32, 256, 0, stream>>>(x, Wt0, as0, ad0, Pb, ALs, ALd, N);
  k_agg128b<<<(N+3)/4, 256, 0, stream>>>(Pb, ALs, ALd, offs, csr, b0, g0, be0, m0, v0, G, N);

  // ---- layer 1 ----
  k_gemm128<<<(N+31)/32, 256, 0, stream>>>(G, Wt1, as1, ad1, Pb, ALs, ALd, N);
  k_agg128b<<<(N+3)/4, 256, 0, stream>>>(Pb, ALs, ALd, offs, csr, b1, g1, be1, m1, v1, G, N);

  // ---- output layer ----
  k_gemm40n<<<(N+63)/64, 256, 0, stream>>>(G, Wt2p, as2, ad2, H2b, al2s, al2d, N);
  k_agg40b<<<(N+7)/8, 256, 0, stream>>>(H2b, al2s, al2d, offs, csr, b2, out, N);
}

// Round 4
// 719.635 us; speedup vs baseline: 1.3906x; 1.0963x over previous
//
#include <hip/hip_runtime.h>
#include <math.h>

#define NEGS 0.2f
#define EPSBN 1e-5f

static __device__ __forceinline__ float lrelu(float x){ return x > 0.f ? x : NEGS*x; }
static __device__ __forceinline__ float bf_lo(unsigned u){ return __uint_as_float(u << 16); }
static __device__ __forceinline__ float bf_hi(unsigned u){ return __uint_as_float(u & 0xffff0000u); }
static __device__ __forceinline__ unsigned short f2bf(float f){
  unsigned u = __float_as_uint(f);
  unsigned r = (u + 0x7fff + ((u >> 16) & 1)) >> 16;   // RNE
  return (unsigned short)r;
}

// ---------------- transpose W [R][C] -> Wt [C][R] ----------------
__global__ void k_transpose(const float* __restrict__ in, float* __restrict__ out, int R, int C){
  int i = blockIdx.x*256 + threadIdx.x;
  if (i >= R*C) return;
  int r = i / C, c = i - r*C;
  out[c*R + r] = in[i];
}

// pad+transpose W2 [40][128] -> Wt2p [128][64] (cols >=40 zero)
__global__ void k_padW2(const float* __restrict__ W2, float* __restrict__ Wt2p){
  int i = blockIdx.x*256 + threadIdx.x;
  if (i >= 128*64) return;
  int k = i >> 6, c = i & 63;
  Wt2p[i] = (c < 40) ? W2[c*128 + k] : 0.f;
}

// ---------------- CSR build ----------------
__global__ void k_deg(const int* __restrict__ ei, int E, int N, int* __restrict__ deg){
  int i = blockIdx.x*256 + threadIdx.x;
  if (i >= E + N) return;
  int d = (i < E) ? ei[E + i] : (i - E);
  atomicAdd(&deg[d], 1);
}

__global__ void k_scan1(const int* __restrict__ deg, int* __restrict__ incl,
                        int* __restrict__ partials, int n){
  __shared__ int sd[256];
  int tid = threadIdx.x;
  int base = blockIdx.x*1024 + tid*4;
  int v[4]; int s = 0;
  #pragma unroll
  for (int j=0;j<4;++j){ int idx = base+j; v[j] = (idx<n)? deg[idx] : 0; s += v[j]; }
  sd[tid] = s; __syncthreads();
  for (int off=1; off<256; off<<=1){
    int t = (tid>=off)? sd[tid-off] : 0;
    __syncthreads();
    sd[tid] += t;
    __syncthreads();
  }
  int run = sd[tid] - s;
  #pragma unroll
  for (int j=0;j<4;++j){ int idx = base+j; run += v[j]; if (idx<n) incl[idx] = run; }
  if (tid==255) partials[blockIdx.x] = sd[255];
}

__global__ void k_scan2(int* partials, int nb){
  __shared__ int sd[256];
  int tid = threadIdx.x;
  sd[tid] = (tid<nb)? partials[tid] : 0;
  __syncthreads();
  for (int off=1; off<256; off<<=1){
    int t = (tid>=off)? sd[tid-off] : 0;
    __syncthreads();
    sd[tid] += t;
    __syncthreads();
  }
  if (tid<nb) partials[tid] = sd[tid];
}

__global__ void k_scan3(int* __restrict__ offs, const int* __restrict__ partials, int n){
  int i = blockIdx.x*256 + threadIdx.x;
  if (i == 0) offs[0] = 0;
  if (i >= n) return;
  int b = i >> 10;
  if (b > 0) offs[i+1] += partials[b-1];
}

__global__ void k_scatter(const int* __restrict__ ei, int E, int N,
                          const int* __restrict__ offs, int* __restrict__ cursor,
                          int* __restrict__ csr){
  int i = blockIdx.x*256 + threadIdx.x;
  if (i >= E + N) return;
  int s, d;
  if (i < E){ s = ei[i]; d = ei[E+i]; } else { s = i - E; d = i - E; }
  int pos = offs[d] + atomicAdd(&cursor[d], 1);
  csr[pos] = s;
}

// ------- GEMM 128x128 (f32 in, bf16 out) + fused attention-logit epilogue -------
__global__ __launch_bounds__(256) void k_gemm128(const float* __restrict__ X,
                                                 const float* __restrict__ Wt,
                                                 const float* __restrict__ as_,
                                                 const float* __restrict__ ad_,
                                                 unsigned short* __restrict__ Yb,
                                                 float* __restrict__ ALs,
                                                 float* __restrict__ ALd, int n){
  __shared__ float xt[128*36];   // xt[k*36 + r], r in [0,32)
  int tid = threadIdx.x;
  int r0 = blockIdx.x * 32;
  {
    int r  = tid & 31;
    int c0 = (tid >> 5) * 16;
    int row = r0 + r;
    const float4* src = (const float4*)(X + (size_t)row*128 + c0);
    #pragma unroll
    for (int j=0;j<4;++j){
      float4 v = (row < n) ? src[j] : make_float4(0.f,0.f,0.f,0.f);
      int k = c0 + j*4;
      xt[(k+0)*36 + r] = v.x;
      xt[(k+1)*36 + r] = v.y;
      xt[(k+2)*36 + r] = v.z;
      xt[(k+3)*36 + r] = v.w;
    }
  }
  __syncthreads();
  int tc = tid & 31, tr = tid >> 5;
  float acc[4][4] = {};
  #pragma unroll 4
  for (int k=0;k<128;++k){
    float4 wv = *(const float4*)(Wt + k*128 + tc*4);
    float4 xv = *(const float4*)(&xt[k*36 + tr*4]);
    float xv4[4] = {xv.x, xv.y, xv.z, xv.w};
    float wv4[4] = {wv.x, wv.y, wv.z, wv.w};
    #pragma unroll
    for (int u=0;u<4;++u)
      #pragma unroll
      for (int v=0;v<4;++v)
        acc[u][v] = fmaf(xv4[u], wv4[v], acc[u][v]);
  }
  // store Y as bf16 (consumed only by the aggregation gather)
  #pragma unroll
  for (int u=0;u<4;++u){
    int row = r0 + tr*4 + u;
    if (row < n){
      ushort4 o;
      o.x = f2bf(acc[u][0]); o.y = f2bf(acc[u][1]);
      o.z = f2bf(acc[u][2]); o.w = f2bf(acc[u][3]);
      *(ushort4*)(Yb + (size_t)row*128 + tc*4) = o;
    }
  }
  // fused attention logits
  int hd = tc >> 3;
  float4 a4 = *(const float4*)(as_ + hd*32 + (tc&7)*4);
  float4 d4 = *(const float4*)(ad_ + hd*32 + (tc&7)*4);
  #pragma unroll
  for (int u=0;u<4;++u){
    float ps = acc[u][0]*a4.x + acc[u][1]*a4.y + acc[u][2]*a4.z + acc[u][3]*a4.w;
    float pd = acc[u][0]*d4.x + acc[u][1]*d4.y + acc[u][2]*d4.z + acc[u][3]*d4.w;
    ps += __shfl_xor(ps,1); ps += __shfl_xor(ps,2); ps += __shfl_xor(ps,4);
    pd += __shfl_xor(pd,1); pd += __shfl_xor(pd,2); pd += __shfl_xor(pd,4);
    int row = r0 + tr*4 + u;
    if ((tc&7)==0 && row < n){ ALs[row*4+hd] = ps; ALd[row*4+hd] = pd; }
  }
}

// ------- fused GAT aggregation + bias + BN + ReLU (bf16 gather, 4 edges/step) -------
// one wave (64 lanes) per node; 16 lanes per edge, ushort8 (16B) per lane
__global__ __launch_bounds__(256) void k_agg128b(const unsigned short* __restrict__ Pb,
                         const float* __restrict__ ALs, const float* __restrict__ ALd,
                         const int* __restrict__ offs, const int* __restrict__ csr,
                         const float* __restrict__ bias, const float* __restrict__ gam,
                         const float* __restrict__ bet, const float* __restrict__ mean,
                         const float* __restrict__ var, float* __restrict__ out, int n){
  int node = blockIdx.x*4 + (threadIdx.x >> 6);
  int lane = threadIdx.x & 63;
  if (node >= n) return;
  int el = lane >> 4, fl = lane & 15, hd = fl >> 2;
  int beg = offs[node], end = offs[node+1];
  int deg = end - beg;
  float aldh = ALd[node*4 + hd];
  int c = (lane < deg) ? csr[beg + lane] : 0;   // preload up to 64 edge indices
  float a0=0.f,a1=0.f,a2=0.f,a3=0.f,a4=0.f,a5=0.f,a6=0.f,a7=0.f;
  float wsum = 0.f;
  int nsteps = (deg + 3) >> 2;
  #pragma unroll 2
  for (int t = 0; t < nsteps; ++t){
    int idx = 4*t + el;
    bool valid = idx < deg;
    int s = (idx < 64) ? __shfl(c, idx) : (valid ? csr[beg + idx] : 0);
    float als = ALs[s*4 + hd];
    float w = valid ? __expf(lrelu(als + aldh)) : 0.f;
    wsum += w;
    uint4 hv = *(const uint4*)(Pb + (size_t)s*128 + fl*8);
    a0 = fmaf(w, bf_lo(hv.x), a0);  a1 = fmaf(w, bf_hi(hv.x), a1);
    a2 = fmaf(w, bf_lo(hv.y), a2);  a3 = fmaf(w, bf_hi(hv.y), a3);
    a4 = fmaf(w, bf_lo(hv.z), a4);  a5 = fmaf(w, bf_hi(hv.z), a5);
    a6 = fmaf(w, bf_lo(hv.w), a6);  a7 = fmaf(w, bf_hi(hv.w), a7);
  }
  #pragma unroll
  for (int off=16; off<64; off<<=1){
    a0 += __shfl_xor(a0, off); a1 += __shfl_xor(a1, off);
    a2 += __shfl_xor(a2, off); a3 += __shfl_xor(a3, off);
    a4 += __shfl_xor(a4, off); a5 += __shfl_xor(a5, off);
    a6 += __shfl_xor(a6, off); a7 += __shfl_xor(a7, off);
    wsum += __shfl_xor(wsum, off);
  }
  if (el == 0){
    float inv = 1.f / wsum;
    int cc = fl*8;
    float4 bA = *(const float4*)(bias+cc), bB = *(const float4*)(bias+cc+4);
    float4 gA = *(const float4*)(gam+cc),  gB = *(const float4*)(gam+cc+4);
    float4 eA = *(const float4*)(bet+cc),  eB = *(const float4*)(bet+cc+4);
    float4 uA = *(const float4*)(mean+cc), uB = *(const float4*)(mean+cc+4);
    float4 vA = *(const float4*)(var+cc),  vB = *(const float4*)(var+cc+4);
    float o0 = (a0*inv + bA.x - uA.x) * rsqrtf(vA.x + EPSBN) * gA.x + eA.x;
    float o1 = (a1*inv + bA.y - uA.y) * rsqrtf(vA.y + EPSBN) * gA.y + eA.y;
    float o2 = (a2*inv + bA.z - uA.z) * rsqrtf(vA.z + EPSBN) * gA.z + eA.z;
    float o3 = (a3*inv + bA.w - uA.w) * rsqrtf(vA.w + EPSBN) * gA.w + eA.w;
    float o4 = (a4*inv + bB.x - uB.x) * rsqrtf(vB.x + EPSBN) * gB.x + eB.x;
    float o5 = (a5*inv + bB.y - uB.y) * rsqrtf(vB.y + EPSBN) * gB.y + eB.y;
    float o6 = (a6*inv + bB.z - uB.z) * rsqrtf(vB.z + EPSBN) * gB.z + eB.z;
    float o7 = (a7*inv + bB.w - uB.w) * rsqrtf(vB.w + EPSBN) * gB.w + eB.w;
    float4* dst = (float4*)(out + (size_t)node*128 + cc);
    dst[0] = make_float4(fmaxf(o0,0.f), fmaxf(o1,0.f), fmaxf(o2,0.f), fmaxf(o3,0.f));
    dst[1] = make_float4(fmaxf(o4,0.f), fmaxf(o5,0.f), fmaxf(o6,0.f), fmaxf(o7,0.f));
  }
}

// ------- output layer GEMM (128->40, padded 64, bf16 H2 out) + fused logits -------
__global__ __launch_bounds__(256) void k_gemm40n(const float* __restrict__ X,
                                                 const float* __restrict__ Wt2p,
                                                 const float* __restrict__ as2,
                                                 const float* __restrict__ ad2,
                                                 unsigned short* __restrict__ H2b,
                                                 float* __restrict__ al2s,
                                                 float* __restrict__ al2d, int n){
  __shared__ float xt[128*68];   // xt[k*68 + r], r in [0,64)
  int tid = threadIdx.x;
  int r0 = blockIdx.x * 64;
  {
    int r  = tid & 63;
    int c0 = (tid >> 6) * 32;
    int row = r0 + r;
    const float4* src = (const float4*)(X + (size_t)row*128 + c0);
    #pragma unroll
    for (int j=0;j<8;++j){
      float4 v = (row < n) ? src[j] : make_float4(0.f,0.f,0.f,0.f);
      int k = c0 + j*4;
      xt[(k+0)*68 + r] = v.x;
      xt[(k+1)*68 + r] = v.y;
      xt[(k+2)*68 + r] = v.z;
      xt[(k+3)*68 + r] = v.w;
    }
  }
  __syncthreads();
  int tc = tid & 15, tr = tid >> 4;
  float acc[4][4] = {};
  #pragma unroll 4
  for (int k=0;k<128;++k){
    float4 wv = *(const float4*)(Wt2p + k*64 + tc*4);
    float4 xv = *(const float4*)(&xt[k*68 + tr*4]);
    float xv4[4] = {xv.x, xv.y, xv.z, xv.w};
    float wv4[4] = {wv.x, wv.y, wv.z, wv.w};
    #pragma unroll
    for (int u=0;u<4;++u)
      #pragma unroll
      for (int v=0;v<4;++v)
        acc[u][v] = fmaf(xv4[u], wv4[v], acc[u][v]);
  }
  float4 a4 = make_float4(0.f,0.f,0.f,0.f), d4 = a4;
  if (tc < 10){
    a4 = *(const float4*)(as2 + tc*4);
    d4 = *(const float4*)(ad2 + tc*4);
  }
  #pragma unroll
  for (int u=0;u<4;++u){
    int row = r0 + tr*4 + u;
    float ps = acc[u][0]*a4.x + acc[u][1]*a4.y + acc[u][2]*a4.z + acc[u][3]*a4.w;
    float pd = acc[u][0]*d4.x + acc[u][1]*d4.y + acc[u][2]*d4.z + acc[u][3]*d4.w;
    #pragma unroll
    for (int m=1; m<16; m<<=1){ ps += __shfl_xor(ps,m); pd += __shfl_xor(pd,m); }
    if (row < n){
      if (tc < 10){
        ushort4 o;
        o.x = f2bf(acc[u][0]); o.y = f2bf(acc[u][1]);
        o.z = f2bf(acc[u][2]); o.w = f2bf(acc[u][3]);
        *(ushort4*)(H2b + (size_t)row*40 + tc*4) = o;
      }
      if (tc == 0){ al2s[row] = ps; al2d[row] = pd; }
    }
  }
}

// ------- output aggregation + bias + log_softmax (bf16 gather, 8 edges/step) -------
// one wave (64 lanes) per node; 8 lanes per edge, 5 active with ushort8 (16B)
__global__ __launch_bounds__(256) void k_agg40b(const unsigned short* __restrict__ H2b,
                        const float* __restrict__ ALs, const float* __restrict__ ALd,
                        const int* __restrict__ offs, const int* __restrict__ csr,
                        const float* __restrict__ b2, float* __restrict__ out, int n){
  int node = blockIdx.x*4 + (threadIdx.x >> 6);
  int lane = threadIdx.x & 63;
  if (node >= n) return;
  int el = lane >> 3, fl = lane & 7;
  bool act = fl < 5;
  int beg = offs[node], end = offs[node+1];
  int deg = end - beg;
  float ald = ALd[node];
  int c = (lane < deg) ? csr[beg + lane] : 0;
  float a0=0.f,a1=0.f,a2=0.f,a3=0.f,a4=0.f,a5=0.f,a6=0.f,a7=0.f;
  float wsum = 0.f;
  int nsteps = (deg + 7) >> 3;
  #pragma unroll 2
  for (int t = 0; t < nsteps; ++t){
    int idx = 8*t + el;
    bool valid = idx < deg;
    int s = (idx < 64) ? __shfl(c, idx) : (valid ? csr[beg + idx] : 0);
    float w = valid ? __expf(lrelu(ALs[s] + ald)) : 0.f;
    wsum += w;
    if (act){
      uint4 hv = *(const uint4*)(H2b + (size_t)s*40 + fl*8);
      a0 = fmaf(w, bf_lo(hv.x), a0);  a1 = fmaf(w, bf_hi(hv.x), a1);
      a2 = fmaf(w, bf_lo(hv.y), a2);  a3 = fmaf(w, bf_hi(hv.y), a3);
      a4 = fmaf(w, bf_lo(hv.z), a4);  a5 = fmaf(w, bf_hi(hv.z), a5);
      a6 = fmaf(w, bf_lo(hv.w), a6);  a7 = fmaf(w, bf_hi(hv.w), a7);
    }
  }
  #pragma unroll
  for (int off=8; off<64; off<<=1){
    a0 += __shfl_xor(a0, off); a1 += __shfl_xor(a1, off);
    a2 += __shfl_xor(a2, off); a3 += __shfl_xor(a3, off);
    a4 += __shfl_xor(a4, off); a5 += __shfl_xor(a5, off);
    a6 += __shfl_xor(a6, off); a7 += __shfl_xor(a7, off);
    wsum += __shfl_xor(wsum, off);
  }
  if (el == 0){
    float inv = 1.f / wsum;
    float y0=0.f,y1=0.f,y2=0.f,y3=0.f,y4=0.f,y5=0.f,y6=0.f,y7=0.f;
    if (act){
      int cc = fl*8;
      float4 bA = *(const float4*)(b2 + cc), bB = *(const float4*)(b2 + cc + 4);
      y0 = a0*inv + bA.x; y1 = a1*inv + bA.y; y2 = a2*inv + bA.z; y3 = a3*inv + bA.w;
      y4 = a4*inv + bB.x; y5 = a5*inv + bB.y; y6 = a6*inv + bB.z; y7 = a7*inv + bB.w;
    }
    float lm = act ? fmaxf(fmaxf(fmaxf(y0,y1),fmaxf(y2,y3)),
                           fmaxf(fmaxf(y4,y5),fmaxf(y6,y7))) : -1e30f;
    lm = fmaxf(lm, __shfl_xor(lm,1));
    lm = fmaxf(lm, __shfl_xor(lm,2));
    lm = fmaxf(lm, __shfl_xor(lm,4));
    float ls = act ? (__expf(y0-lm)+__expf(y1-lm)+__expf(y2-lm)+__expf(y3-lm)
                     +__expf(y4-lm)+__expf(y5-lm)+__expf(y6-lm)+__expf(y7-lm)) : 0.f;
    ls += __shfl_xor(ls,1);
    ls += __shfl_xor(ls,2);
    ls += __shfl_xor(ls,4);
    float lg = lm + __logf(ls);
    if (act){
      float4* dst = (float4*)(out + (size_t)node*40 + fl*8);
      dst[0] = make_float4(y0-lg, y1-lg, y2-lg, y3-lg);
      dst[1] = make_float4(y4-lg, y5-lg, y6-lg, y7-lg);
    }
  }
}

extern "C" void kernel_launch(void* const* d_in, const int* in_sizes, int n_in,
                              void* d_out, int out_size, void* d_ws, size_t ws_size,
                              hipStream_t stream) {
  const float* x   = (const float*)d_in[0];
  const int*   ei  = (const int*)d_in[1];
  const float* W0  = (const float*)d_in[2];
  const float* as0 = (const float*)d_in[3];
  const float* ad0 = (const float*)d_in[4];
  const float* b0  = (const float*)d_in[5];
  const float* g0  = (const float*)d_in[6];
  const float* be0 = (const float*)d_in[7];
  const float* m0  = (const float*)d_in[8];
  const float* v0  = (const float*)d_in[9];
  const float* W1  = (const float*)d_in[10];
  const float* as1 = (const float*)d_in[11];
  const float* ad1 = (const float*)d_in[12];
  const float* b1  = (const float*)d_in[13];
  const float* g1  = (const float*)d_in[14];
  const float* be1 = (const float*)d_in[15];
  const float* m1  = (const float*)d_in[16];
  const float* v1  = (const float*)d_in[17];
  const float* W2  = (const float*)d_in[18];
  const float* as2 = (const float*)d_in[19];
  const float* ad2 = (const float*)d_in[20];
  const float* b2  = (const float*)d_in[21];
  float* out = (float*)d_out;

  int N = in_sizes[0] / 128;
  int E = in_sizes[1] / 2;
  int ET = E + N;

  char* p = (char*)d_ws;
  auto alloc = [&](size_t bytes)->void* {
    void* r = (void*)p;
    p += (bytes + 255) & ~size_t(255);
    return r;
  };
  float* Wt0 = (float*)alloc((size_t)128*128*4);
  float* Wt1 = (float*)alloc((size_t)128*128*4);
  float* Wt2p= (float*)alloc((size_t)128*64*4);
  int* deg     = (int*)alloc((size_t)N*4);
  int* cursor  = (int*)alloc((size_t)N*4);
  int* offs    = (int*)alloc((size_t)(N+1)*4);
  int* partials= (int*)alloc(1024*4);
  int* csr     = (int*)alloc((size_t)ET*4);
  unsigned short* Pb = (unsigned short*)alloc((size_t)N*128*2);
  float* G   = (float*)alloc((size_t)N*128*4);
  float* ALs = (float*)alloc((size_t)N*4*4);
  float* ALd = (float*)alloc((size_t)N*4*4);
  unsigned short* H2b = Pb;     // Pb free by the time layer-2 GEMM runs
  float* al2s = ALs;
  float* al2d = ALd;
  if ((size_t)(p - (char*)d_ws) > ws_size) return;  // workspace too small

  // deg and cursor are adjacent 256B-aligned allocations: one memset covers both
  size_t degpad = ((size_t)N*4 + 255) & ~size_t(255);
  hipMemsetAsync(deg, 0, degpad + (size_t)N*4, stream);

  // weight prep
  k_transpose<<<(128*128+255)/256, 256, 0, stream>>>(W0, Wt0, 128, 128);
  k_transpose<<<(128*128+255)/256, 256, 0, stream>>>(W1, Wt1, 128, 128);
  k_padW2<<<(128*64+255)/256, 256, 0, stream>>>(W2, Wt2p);

  // CSR build (dst-sorted)
  int nb_scan = (N + 1023) / 1024;
  k_deg<<<(ET+255)/256, 256, 0, stream>>>(ei, E, N, deg);
  k_scan1<<<nb_scan, 256, 0, stream>>>(deg, offs+1, partials, N);
  k_scan2<<<1, 256, 0, stream>>>(partials, nb_scan);
  k_scan3<<<(N+255)/256, 256, 0, stream>>>(offs, partials, N);
  k_scatter<<<(ET+255)/256, 256, 0, stream>>>(ei, E, N, offs, cursor, csr);

  // ---- layer 0 ----
  k_gemm128<<<(N+31)/32, 256, 0, stream>>>(x, Wt0, as0, ad0, Pb, ALs, ALd, N);
  k_agg128b<<<(N+3)/4, 256, 0, stream>>>(Pb, ALs, ALd, offs, csr, b0, g0, be0, m0, v0, G, N);

  // ---- layer 1 ----
  k_gemm128<<<(N+31)/32, 256, 0, stream>>>(G, Wt1, as1, ad1, Pb, ALs, ALd, N);
  k_agg128b<<<(N+3)/4, 256, 0, stream>>>(Pb, ALs, ALd, offs, csr, b1, g1, be1, m1, v1, G, N);

  // ---- output layer ----
  k_gemm40n<<<(N+63)/64, 256, 0, stream>>>(G, Wt2p, as2, ad2, H2b, al2s, al2d, N);
  k_agg40b<<<(N+3)/4, 256, 0, stream>>>(H2b, al2s, al2d, offs, csr, b2, out, N);
}

// Round 5
// 652.708 us; speedup vs baseline: 1.5332x; 1.1025x over previous
//
#include <hip/hip_runtime.h>
#include <math.h>

#define NEGS 0.2f
#define EPSBN 1e-5f

typedef __attribute__((ext_vector_type(8))) short short8v;   // 8 bf16 = 4 VGPR
typedef __attribute__((ext_vector_type(4))) float f32x4;     // MFMA acc

static __device__ __forceinline__ float lrelu(float x){ return x > 0.f ? x : NEGS*x; }
static __device__ __forceinline__ float bf_lo(unsigned u){ return __uint_as_float(u << 16); }
static __device__ __forceinline__ float bf_hi(unsigned u){ return __uint_as_float(u & 0xffff0000u); }
static __device__ __forceinline__ float bf1(unsigned short v){ return __uint_as_float(((unsigned)v) << 16); }
static __device__ __forceinline__ unsigned short f2bf(float f){
  unsigned u = __float_as_uint(f);
  unsigned r = (u + 0x7fff + ((u >> 16) & 1)) >> 16;   // RNE
  return (unsigned short)r;
}

// pad+transpose W2 [40][128] -> Wt2p [128][64] (cols >=40 zero)
__global__ void k_padW2(const float* __restrict__ W2, float* __restrict__ Wt2p){
  int i = blockIdx.x*256 + threadIdx.x;
  if (i >= 128*64) return;
  int k = i >> 6, c = i & 63;
  Wt2p[i] = (c < 40) ? W2[c*128 + k] : 0.f;
}

// ---------------- CSR build ----------------
__global__ void k_deg(const int* __restrict__ ei, int E, int N, int* __restrict__ deg){
  int i = blockIdx.x*256 + threadIdx.x;
  if (i >= E + N) return;
  int d = (i < E) ? ei[E + i] : (i - E);
  atomicAdd(&deg[d], 1);
}

__global__ void k_scan1(const int* __restrict__ deg, int* __restrict__ incl,
                        int* __restrict__ partials, int n){
  __shared__ int sd[256];
  int tid = threadIdx.x;
  int base = blockIdx.x*1024 + tid*4;
  int v[4]; int s = 0;
  #pragma unroll
  for (int j=0;j<4;++j){ int idx = base+j; v[j] = (idx<n)? deg[idx] : 0; s += v[j]; }
  sd[tid] = s; __syncthreads();
  for (int off=1; off<256; off<<=1){
    int t = (tid>=off)? sd[tid-off] : 0;
    __syncthreads();
    sd[tid] += t;
    __syncthreads();
  }
  int run = sd[tid] - s;
  #pragma unroll
  for (int j=0;j<4;++j){ int idx = base+j; run += v[j]; if (idx<n) incl[idx] = run; }
  if (tid==255) partials[blockIdx.x] = sd[255];
}

__global__ void k_scan2(int* partials, int nb){
  __shared__ int sd[256];
  int tid = threadIdx.x;
  sd[tid] = (tid<nb)? partials[tid] : 0;
  __syncthreads();
  for (int off=1; off<256; off<<=1){
    int t = (tid>=off)? sd[tid-off] : 0;
    __syncthreads();
    sd[tid] += t;
    __syncthreads();
  }
  if (tid<nb) partials[tid] = sd[tid];
}

__global__ void k_scan3(int* __restrict__ offs, const int* __restrict__ partials, int n){
  int i = blockIdx.x*256 + threadIdx.x;
  if (i == 0) offs[0] = 0;
  if (i >= n) return;
  int b = i >> 10;
  if (b > 0) offs[i+1] += partials[b-1];
}

__global__ void k_scatter(const int* __restrict__ ei, int E, int N,
                          const int* __restrict__ offs, int* __restrict__ cursor,
                          int* __restrict__ csr){
  int i = blockIdx.x*256 + threadIdx.x;
  if (i >= E + N) return;
  int s, d;
  if (i < E){ s = ei[i]; d = ei[E+i]; } else { s = i - E; d = i - E; }
  int pos = offs[d] + atomicAdd(&cursor[d], 1);
  csr[pos] = s;
}

// ------- MFMA GEMM 128x128 (X f32 or bf16 in, bf16 out) + fused logits -------
// block = 256 (4 waves), tile = 64 rows x 128 cols, W[o][k] row-major is the
// B-operand layout directly (lane needs 8 consecutive k at fixed o).
// LDS XOR-swizzle dw ^= (row&7)<<2 kills the stride-128B bank conflict (G4).
template<bool BF16IN>
__global__ __launch_bounds__(256) void k_gemm128m(const void* __restrict__ Xin,
                          const float* __restrict__ W,
                          const float* __restrict__ as_, const float* __restrict__ ad_,
                          unsigned short* __restrict__ Yb,
                          float* __restrict__ ALs, float* __restrict__ ALd, int n){
  __shared__ short lds[24576];               // Wb 128x128 @0 (32KB), Xb 64x128 @16384 (16KB)
  unsigned* ldsW = (unsigned*)lds;           // 8192 dwords
  unsigned* ldsX = (unsigned*)(lds + 16384); // 4096 dwords
  int tid = threadIdx.x;
  int r0 = blockIdx.x*64;
  // stage W (f32 -> bf16, swizzled)
  #pragma unroll
  for (int j=0;j<16;++j){
    int i = (256*j + tid)*4;
    int row = i >> 7;
    float4 v = *(const float4*)(W + i);
    int dw = i >> 1, lo = dw & 63, base = dw & ~63;
    int sw = base | (lo ^ ((row&7)<<2));
    uint2 p;
    p.x = (unsigned)f2bf(v.x) | ((unsigned)f2bf(v.y)<<16);
    p.y = (unsigned)f2bf(v.z) | ((unsigned)f2bf(v.w)<<16);
    *(uint2*)(&ldsW[sw]) = p;
  }
  // stage X tile
  if (!BF16IN){
    const float* X = (const float*)Xin;
    #pragma unroll
    for (int j=0;j<8;++j){
      int i = (256*j + tid)*4;
      int row = i >> 7;
      int grow = r0 + row;
      float4 v = (grow < n) ? *(const float4*)(X + (size_t)grow*128 + (i&127))
                            : make_float4(0.f,0.f,0.f,0.f);
      int dw = i >> 1, lo = dw & 63, base = dw & ~63;
      int sw = base | (lo ^ ((row&7)<<2));
      uint2 p;
      p.x = (unsigned)f2bf(v.x) | ((unsigned)f2bf(v.y)<<16);
      p.y = (unsigned)f2bf(v.z) | ((unsigned)f2bf(v.w)<<16);
      *(uint2*)(&ldsX[sw]) = p;
    }
  } else {
    const unsigned short* Xb = (const unsigned short*)Xin;
    #pragma unroll
    for (int j=0;j<4;++j){
      int dw4 = 1024*j + tid*4;
      int row = dw4 >> 6;
      int grow = r0 + row;
      uint4 v = (grow < n) ? *(const uint4*)(Xb + (size_t)grow*128 + (dw4&63)*2)
                           : make_uint4(0,0,0,0);
      int lo = dw4 & 63, base = dw4 & ~63;
      int sw = base | (lo ^ ((row&7)<<2));
      *(uint4*)(&ldsX[sw]) = v;
    }
  }
  __syncthreads();
  int l = tid & 63, w = tid >> 6;
  int lrow = l & 15, lk = l >> 4;
  // A fragments (4 k-steps), row = w*16 + lrow
  int arow = w*16 + lrow;
  int abase = arow*64, ax = (arow&7)<<2;
  short8v a[4];
  #pragma unroll
  for (int ks=0;ks<4;++ks){
    int lo = ks*16 + lk*4;
    a[ks] = *(const short8v*)&ldsX[abase + (lo ^ ax)];
  }
  f32x4 acc[8];
  #pragma unroll
  for (int c=0;c<8;++c) acc[c] = (f32x4){0.f,0.f,0.f,0.f};
  #pragma unroll
  for (int c=0;c<8;++c){
    int brow = c*16 + lrow;
    int bbase = brow*64, bx = (brow&7)<<2;
    #pragma unroll
    for (int ks=0;ks<4;++ks){
      int lo = ks*16 + lk*4;
      short8v b = *(const short8v*)&ldsW[bbase + (lo ^ bx)];
      acc[c] = __builtin_amdgcn_mfma_f32_16x16x32_bf16(a[ks], b, acc[c], 0, 0, 0);
    }
  }
  __syncthreads();
  // stash D tile to LDS (bf16, linear) over the Xb area
  unsigned short* Ys = (unsigned short*)ldsX;
  #pragma unroll
  for (int c=0;c<8;++c){
    #pragma unroll
    for (int r=0;r<4;++r){
      int row = w*16 + lk*4 + r;
      Ys[row*128 + c*16 + lrow] = f2bf(acc[c][r]);
    }
  }
  __syncthreads();
  // coalesced global store of the bf16 tile
  #pragma unroll
  for (int j=0;j<4;++j){
    int dw4 = 1024*j + tid*4;
    int row = dw4 >> 6;
    int grow = r0 + row;
    if (grow < n)
      *(uint4*)(Yb + (size_t)grow*128 + (dw4&63)*2) = *(const uint4*)&((unsigned*)ldsX)[dw4];
  }
  // fused logits: thread -> (row = tid>>2, head = tid&3), 64 rows x 4 heads = 256
  {
    int row = tid >> 2, h = tid & 3;
    int grow = r0 + row;
    if (grow < n){
      const unsigned short* yr = Ys + row*128 + h*32;
      float ps = 0.f, pd = 0.f;
      #pragma unroll
      for (int j=0;j<32;++j){
        float y = bf1(yr[j]);
        ps = fmaf(y, as_[h*32+j], ps);
        pd = fmaf(y, ad_[h*32+j], pd);
      }
      ALs[grow*4+h] = ps; ALd[grow*4+h] = pd;
    }
  }
}

// ------- fused GAT aggregation + bias + BN + ReLU (bf16 gather, 4 edges/step, bf16 out) -------
__global__ __launch_bounds__(256) void k_agg128b(const unsigned short* __restrict__ Pb,
                         const float* __restrict__ ALs, const float* __restrict__ ALd,
                         const int* __restrict__ offs, const int* __restrict__ csr,
                         const float* __restrict__ bias, const float* __restrict__ gam,
                         const float* __restrict__ bet, const float* __restrict__ mean,
                         const float* __restrict__ var, unsigned short* __restrict__ outb, int n){
  int node = blockIdx.x*4 + (threadIdx.x >> 6);
  int lane = threadIdx.x & 63;
  if (node >= n) return;
  int el = lane >> 4, fl = lane & 15, hd = fl >> 2;
  int beg = offs[node], end = offs[node+1];
  int deg = end - beg;
  float aldh = ALd[node*4 + hd];
  int c = (lane < deg) ? csr[beg + lane] : 0;
  float a0=0.f,a1=0.f,a2=0.f,a3=0.f,a4=0.f,a5=0.f,a6=0.f,a7=0.f;
  float wsum = 0.f;
  int nsteps = (deg + 3) >> 2;
  #pragma unroll 2
  for (int t = 0; t < nsteps; ++t){
    int idx = 4*t + el;
    bool valid = idx < deg;
    int s = (idx < 64) ? __shfl(c, idx) : (valid ? csr[beg + idx] : 0);
    float als = ALs[s*4 + hd];
    float w = valid ? __expf(lrelu(als + aldh)) : 0.f;
    wsum += w;
    uint4 hv = *(const uint4*)(Pb + (size_t)s*128 + fl*8);
    a0 = fmaf(w, bf_lo(hv.x), a0);  a1 = fmaf(w, bf_hi(hv.x), a1);
    a2 = fmaf(w, bf_lo(hv.y), a2);  a3 = fmaf(w, bf_hi(hv.y), a3);
    a4 = fmaf(w, bf_lo(hv.z), a4);  a5 = fmaf(w, bf_hi(hv.z), a5);
    a6 = fmaf(w, bf_lo(hv.w), a6);  a7 = fmaf(w, bf_hi(hv.w), a7);
  }
  #pragma unroll
  for (int off=16; off<64; off<<=1){
    a0 += __shfl_xor(a0, off); a1 += __shfl_xor(a1, off);
    a2 += __shfl_xor(a2, off); a3 += __shfl_xor(a3, off);
    a4 += __shfl_xor(a4, off); a5 += __shfl_xor(a5, off);
    a6 += __shfl_xor(a6, off); a7 += __shfl_xor(a7, off);
    wsum += __shfl_xor(wsum, off);
  }
  if (el == 0){
    float inv = 1.f / wsum;
    int cc = fl*8;
    float4 bA = *(const float4*)(bias+cc), bB = *(const float4*)(bias+cc+4);
    float4 gA = *(const float4*)(gam+cc),  gB = *(const float4*)(gam+cc+4);
    float4 eA = *(const float4*)(bet+cc),  eB = *(const float4*)(bet+cc+4);
    float4 uA = *(const float4*)(mean+cc), uB = *(const float4*)(mean+cc+4);
    float4 vA = *(const float4*)(var+cc),  vB = *(const float4*)(var+cc+4);
    float o0 = (a0*inv + bA.x - uA.x) * rsqrtf(vA.x + EPSBN) * gA.x + eA.x;
    float o1 = (a1*inv + bA.y - uA.y) * rsqrtf(vA.y + EPSBN) * gA.y + eA.y;
    float o2 = (a2*inv + bA.z - uA.z) * rsqrtf(vA.z + EPSBN) * gA.z + eA.z;
    float o3 = (a3*inv + bA.w - uA.w) * rsqrtf(vA.w + EPSBN) * gA.w + eA.w;
    float o4 = (a4*inv + bB.x - uB.x) * rsqrtf(vB.x + EPSBN) * gB.x + eB.x;
    float o5 = (a5*inv + bB.y - uB.y) * rsqrtf(vB.y + EPSBN) * gB.y + eB.y;
    float o6 = (a6*inv + bB.z - uB.z) * rsqrtf(vB.z + EPSBN) * gB.z + eB.z;
    float o7 = (a7*inv + bB.w - uB.w) * rsqrtf(vB.w + EPSBN) * gB.w + eB.w;
    uint4 q;
    q.x = (unsigned)f2bf(fmaxf(o0,0.f)) | ((unsigned)f2bf(fmaxf(o1,0.f))<<16);
    q.y = (unsigned)f2bf(fmaxf(o2,0.f)) | ((unsigned)f2bf(fmaxf(o3,0.f))<<16);
    q.z = (unsigned)f2bf(fmaxf(o4,0.f)) | ((unsigned)f2bf(fmaxf(o5,0.f))<<16);
    q.w = (unsigned)f2bf(fmaxf(o6,0.f)) | ((unsigned)f2bf(fmaxf(o7,0.f))<<16);
    *(uint4*)(outb + (size_t)node*128 + cc) = q;
  }
}

// ------- output layer GEMM (bf16 in, 128->40 padded 64, bf16 H2 out) + fused logits -------
__global__ __launch_bounds__(256) void k_gemm40n(const unsigned short* __restrict__ Gb,
                                                 const float* __restrict__ Wt2p,
                                                 const float* __restrict__ as2,
                                                 const float* __restrict__ ad2,
                                                 unsigned short* __restrict__ H2b,
                                                 float* __restrict__ al2s,
                                                 float* __restrict__ al2d, int n){
  __shared__ float xt[128*68];   // xt[k*68 + r], r in [0,64)
  int tid = threadIdx.x;
  int r0 = blockIdx.x * 64;
  {
    int r  = tid & 63;
    int c0 = (tid >> 6) * 32;
    int row = r0 + r;
    #pragma unroll
    for (int j=0;j<4;++j){
      uint4 v = (row < n) ? *(const uint4*)(Gb + (size_t)row*128 + c0 + j*8)
                          : make_uint4(0,0,0,0);
      int k = c0 + j*8;
      xt[(k+0)*68 + r] = bf_lo(v.x);  xt[(k+1)*68 + r] = bf_hi(v.x);
      xt[(k+2)*68 + r] = bf_lo(v.y);  xt[(k+3)*68 + r] = bf_hi(v.y);
      xt[(k+4)*68 + r] = bf_lo(v.z);  xt[(k+5)*68 + r] = bf_hi(v.z);
      xt[(k+6)*68 + r] = bf_lo(v.w);  xt[(k+7)*68 + r] = bf_hi(v.w);
    }
  }
  __syncthreads();
  int tc = tid & 15, tr = tid >> 4;
  float acc[4][4] = {};
  #pragma unroll 4
  for (int k=0;k<128;++k){
    float4 wv = *(const float4*)(Wt2p + k*64 + tc*4);
    float4 xv = *(const float4*)(&xt[k*68 + tr*4]);
    float xv4[4] = {xv.x, xv.y, xv.z, xv.w};
    float wv4[4] = {wv.x, wv.y, wv.z, wv.w};
    #pragma unroll
    for (int u=0;u<4;++u)
      #pragma unroll
      for (int v=0;v<4;++v)
        acc[u][v] = fmaf(xv4[u], wv4[v], acc[u][v]);
  }
  float4 a4 = make_float4(0.f,0.f,0.f,0.f), d4 = a4;
  if (tc < 10){
    a4 = *(const float4*)(as2 + tc*4);
    d4 = *(const float4*)(ad2 + tc*4);
  }
  #pragma unroll
  for (int u=0;u<4;++u){
    int row = r0 + tr*4 + u;
    float ps = acc[u][0]*a4.x + acc[u][1]*a4.y + acc[u][2]*a4.z + acc[u][3]*a4.w;
    float pd = acc[u][0]*d4.x + acc[u][1]*d4.y + acc[u][2]*d4.z + acc[u][3]*d4.w;
    #pragma unroll
    for (int m=1; m<16; m<<=1){ ps += __shfl_xor(ps,m); pd += __shfl_xor(pd,m); }
    if (row < n){
      if (tc < 10){
        ushort4 o;
        o.x = f2bf(acc[u][0]); o.y = f2bf(acc[u][1]);
        o.z = f2bf(acc[u][2]); o.w = f2bf(acc[u][3]);
        *(ushort4*)(H2b + (size_t)row*40 + tc*4) = o;
      }
      if (tc == 0){ al2s[row] = ps; al2d[row] = pd; }
    }
  }
}

// ------- output aggregation + bias + log_softmax (bf16 gather, 8 edges/step) -------
__global__ __launch_bounds__(256) void k_agg40b(const unsigned short* __restrict__ H2b,
                        const float* __restrict__ ALs, const float* __restrict__ ALd,
                        const int* __restrict__ offs, const int* __restrict__ csr,
                        const float* __restrict__ b2, float* __restrict__ out, int n){
  int node = blockIdx.x*4 + (threadIdx.x >> 6);
  int lane = threadIdx.x & 63;
  if (node >= n) return;
  int el = lane >> 3, fl = lane & 7;
  bool act = fl < 5;
  int beg = offs[node], end = offs[node+1];
  int deg = end - beg;
  float ald = ALd[node];
  int c = (lane < deg) ? csr[beg + lane] : 0;
  float a0=0.f,a1=0.f,a2=0.f,a3=0.f,a4=0.f,a5=0.f,a6=0.f,a7=0.f;
  float wsum = 0.f;
  int nsteps = (deg + 7) >> 3;
  #pragma unroll 2
  for (int t = 0; t < nsteps; ++t){
    int idx = 8*t + el;
    bool valid = idx < deg;
    int s = (idx < 64) ? __shfl(c, idx) : (valid ? csr[beg + idx] : 0);
    float w = valid ? __expf(lrelu(ALs[s] + ald)) : 0.f;
    wsum += w;
    if (act){
      uint4 hv = *(const uint4*)(H2b + (size_t)s*40 + fl*8);
      a0 = fmaf(w, bf_lo(hv.x), a0);  a1 = fmaf(w, bf_hi(hv.x), a1);
      a2 = fmaf(w, bf_lo(hv.y), a2);  a3 = fmaf(w, bf_hi(hv.y), a3);
      a4 = fmaf(w, bf_lo(hv.z), a4);  a5 = fmaf(w, bf_hi(hv.z), a5);
      a6 = fmaf(w, bf_lo(hv.w), a6);  a7 = fmaf(w, bf_hi(hv.w), a7);
    }
  }
  #pragma unroll
  for (int off=8; off<64; off<<=1){
    a0 += __shfl_xor(a0, off); a1 += __shfl_xor(a1, off);
    a2 += __shfl_xor(a2, off); a3 += __shfl_xor(a3, off);
    a4 += __shfl_xor(a4, off); a5 += __shfl_xor(a5, off);
    a6 += __shfl_xor(a6, off); a7 += __shfl_xor(a7, off);
    wsum += __shfl_xor(wsum, off);
  }
  if (el == 0){
    float inv = 1.f / wsum;
    float y0=0.f,y1=0.f,y2=0.f,y3=0.f,y4=0.f,y5=0.f,y6=0.f,y7=0.f;
    if (act){
      int cc = fl*8;
      float4 bA = *(const float4*)(b2 + cc), bB = *(const float4*)(b2 + cc + 4);
      y0 = a0*inv + bA.x; y1 = a1*inv + bA.y; y2 = a2*inv + bA.z; y3 = a3*inv + bA.w;
      y4 = a4*inv + bB.x; y5 = a5*inv + bB.y; y6 = a6*inv + bB.z; y7 = a7*inv + bB.w;
    }
    float lm = act ? fmaxf(fmaxf(fmaxf(y0,y1),fmaxf(y2,y3)),
                           fmaxf(fmaxf(y4,y5),fmaxf(y6,y7))) : -1e30f;
    lm = fmaxf(lm, __shfl_xor(lm,1));
    lm = fmaxf(lm, __shfl_xor(lm,2));
    lm = fmaxf(lm, __shfl_xor(lm,4));
    float ls = act ? (__expf(y0-lm)+__expf(y1-lm)+__expf(y2-lm)+__expf(y3-lm)
                     +__expf(y4-lm)+__expf(y5-lm)+__expf(y6-lm)+__expf(y7-lm)) : 0.f;
    ls += __shfl_xor(ls,1);
    ls += __shfl_xor(ls,2);
    ls += __shfl_xor(ls,4);
    float lg = lm + __logf(ls);
    if (act){
      float4* dst = (float4*)(out + (size_t)node*40 + fl*8);
      dst[0] = make_float4(y0-lg, y1-lg, y2-lg, y3-lg);
      dst[1] = make_float4(y4-lg, y5-lg, y6-lg, y7-lg);
    }
  }
}

extern "C" void kernel_launch(void* const* d_in, const int* in_sizes, int n_in,
                              void* d_out, int out_size, void* d_ws, size_t ws_size,
                              hipStream_t stream) {
  const float* x   = (const float*)d_in[0];
  const int*   ei  = (const int*)d_in[1];
  const float* W0  = (const float*)d_in[2];
  const float* as0 = (const float*)d_in[3];
  const float* ad0 = (const float*)d_in[4];
  const float* b0  = (const float*)d_in[5];
  const float* g0  = (const float*)d_in[6];
  const float* be0 = (const float*)d_in[7];
  const float* m0  = (const float*)d_in[8];
  const float* v0  = (const float*)d_in[9];
  const float* W1  = (const float*)d_in[10];
  const float* as1 = (const float*)d_in[11];
  const float* ad1 = (const float*)d_in[12];
  const float* b1  = (const float*)d_in[13];
  const float* g1  = (const float*)d_in[14];
  const float* be1 = (const float*)d_in[15];
  const float* m1  = (const float*)d_in[16];
  const float* v1  = (const float*)d_in[17];
  const float* W2  = (const float*)d_in[18];
  const float* as2 = (const float*)d_in[19];
  const float* ad2 = (const float*)d_in[20];
  const float* b2  = (const float*)d_in[21];
  float* out = (float*)d_out;

  int N = in_sizes[0] / 128;
  int E = in_sizes[1] / 2;
  int ET = E + N;

  char* p = (char*)d_ws;
  auto alloc = [&](size_t bytes)->void* {
    void* r = (void*)p;
    p += (bytes + 255) & ~size_t(255);
    return r;
  };
  float* Wt2p  = (float*)alloc((size_t)128*64*4);
  int* deg     = (int*)alloc((size_t)N*4);
  int* cursor  = (int*)alloc((size_t)N*4);
  int* offs    = (int*)alloc((size_t)(N+1)*4);
  int* partials= (int*)alloc(1024*4);
  int* csr     = (int*)alloc((size_t)ET*4);
  unsigned short* Pb = (unsigned short*)alloc((size_t)N*128*2);
  unsigned short* Gb = (unsigned short*)alloc((size_t)N*128*2);
  float* ALs = (float*)alloc((size_t)N*4*4);
  float* ALd = (float*)alloc((size_t)N*4*4);
  unsigned short* H2b = Pb;     // Pb free by the time layer-2 GEMM runs
  float* al2s = ALs;
  float* al2d = ALd;
  if ((size_t)(p - (char*)d_ws) > ws_size) return;  // workspace too small

  // deg and cursor are adjacent 256B-aligned allocations: one memset covers both
  size_t degpad = ((size_t)N*4 + 255) & ~size_t(255);
  hipMemsetAsync(deg, 0, degpad + (size_t)N*4, stream);

  // weight prep (only W2 needs transpose+pad; W0/W1 feed MFMA as-is)
  k_padW2<<<(128*64+255)/256, 256, 0, stream>>>(W2, Wt2p);

  // CSR build (dst-sorted)
  int nb_scan = (N + 1023) / 1024;
  k_deg<<<(ET+255)/256, 256, 0, stream>>>(ei, E, N, deg);
  k_scan1<<<nb_scan, 256, 0, stream>>>(deg, offs+1, partials, N);
  k_scan2<<<1, 256, 0, stream>>>(partials, nb_scan);
  k_scan3<<<(N+255)/256, 256, 0, stream>>>(offs, partials, N);
  k_scatter<<<(ET+255)/256, 256, 0, stream>>>(ei, E, N, offs, cursor, csr);

  int gb = (N + 63) / 64;
  // ---- layer 0 ----
  k_gemm128m<false><<<gb, 256, 0, stream>>>(x, W0, as0, ad0, Pb, ALs, ALd, N);
  k_agg128b<<<(N+3)/4, 256, 0, stream>>>(Pb, ALs, ALd, offs, csr, b0, g0, be0, m0, v0, Gb, N);

  // ---- layer 1 ----
  k_gemm128m<true><<<gb, 256, 0, stream>>>(Gb, W1, as1, ad1, Pb, ALs, ALd, N);
  k_agg128b<<<(N+3)/4, 256, 0, stream>>>(Pb, ALs, ALd, offs, csr, b1, g1, be1, m1, v1, Gb, N);

  // ---- output layer ----
  k_gemm40n<<<gb, 256, 0, stream>>>(Gb, Wt2p, as2, ad2, H2b, al2s, al2d, N);
  k_agg40b<<<(N+3)/4, 256, 0, stream>>>(H2b, al2s, al2d, offs, csr, b2, out, N);
}